// Round 11
// baseline (1136.448 us; speedup 1.0000x reference)
//
#include <hip/hip_runtime.h>
#include <hip/hip_bf16.h>
#include <math.h>

// Problem constants
#define BB 64
#define LL 200
#define NQ 1024
#define DD 256
#define HH 512
#define QQ 1024
#define G3 1536   // 3*H
#define BL 12800  // B*L
#define GBLK 256  // persistent GRU grid: 1 block/CU

// ---------------- workspace layout (in floats) ----------------
#define OFF_ACC   ((size_t)0)                    // [1]=mse [2]=maskcnt ([0] unused now)
#define OFF_CELLS ((size_t)16)                   // 256 cells, 16B apart + done ctr (1024 uints)
#define OFF_HA    ((size_t)1056)                 // hA[2][64][512] batch-major
#define OFF_AQ    (OFF_HA + 65536)               // 1025*1536
#define OFF_DQ    (OFF_AQ + 1574400)
#define OFF_BQA   (OFF_DQ + 1574400)             // 2*1536
#define OFF_CQA   (OFF_BQA + 3072)
#define OFF_CREGS (OFF_CQA + 3072)               // 50 creg partial slots (old wsum area)
#define OFF_FCWT  (OFF_CREGS + 393216)           // (unused)
#define OFF_M2    (OFF_FCWT + 524288)            // 1024*512
#define OFF_MB    (OFF_M2 + 524288)              // 1024
#define OFF_QINT  (OFF_MB + 1024)                // 12800 ints [B][L]
#define OFF_QAINT (OFF_QINT + 12800)
#define OFF_PIDF  (OFF_QAINT + 12800)

typedef float f32x4 __attribute__((ext_vector_type(4)));

__device__ __forceinline__ float wave_sum64(float v) {
    #pragma unroll
    for (int o = 32; o > 0; o >>= 1) v += __shfl_down(v, o, 64);
    return v;
}

// LLC-coherent (bypass L1/L2) ops
__device__ __forceinline__ f32x4 llc_load4(const float* p) {
    f32x4 v;
    asm volatile("global_load_dwordx4 %0, %1, off sc0 sc1" : "=v"(v) : "v"(p));
    return v;
}
__device__ __forceinline__ void llc_wait2(f32x4& a, f32x4& b) {
    asm volatile("s_waitcnt vmcnt(0)" : "+v"(a), "+v"(b));
}
__device__ __forceinline__ void llc_store1(float* p, float v) {
    asm volatile("global_store_dword %0, %1, off sc0 sc1" :: "v"(p), "v"(v) : "memory");
}

// quad (4-lane) butterfly sum via DPP quad_perm (VALU pipe, not LDS)
__device__ __forceinline__ float quad_sum(float v) {
    float t1 = __int_as_float(__builtin_amdgcn_update_dpp(
        0, __float_as_int(v), 0xB1, 0xF, 0xF, true));   // quad_perm xor1
    v += t1;
    float t2 = __int_as_float(__builtin_amdgcn_update_dpp(
        0, __float_as_int(v), 0x4E, 0xF, 0xF, true));   // quad_perm xor2
    return v + t2;
}

// -------- 128x64 NT GEMM tile body (verified compute; optional B = sum of halves) ----
__device__ __forceinline__ void gemm_nt_body(
    const float* __restrict__ A, int lda, const float* __restrict__ B, int ldb,
    float* __restrict__ C, int ldc, int M, int N, int K,
    const float* __restrict__ bias, int bm, int bn, int tid, bool sumB,
    float (*As)[129], float (*Bs)[65])
{
    const int tx = tid & 15, ty = tid >> 4;
    const int mm = tid >> 4, kk = tid & 15;
    float acc[8][4] = {};
    float ar[8], br[4];
    #pragma unroll
    for (int i = 0; i < 8; ++i) {
        int m = bm + mm + 16 * i;
        ar[i] = (m < M) ? A[(size_t)m * lda + kk] : 0.f;
    }
    #pragma unroll
    for (int i = 0; i < 4; ++i) {
        int n = bn + mm + 16 * i;
        br[i] = (n < N) ? (sumB ? (B[(size_t)n * ldb + kk] + B[(size_t)n * ldb + DD + kk])
                                : B[(size_t)n * ldb + kk]) : 0.f;
    }
    for (int k0 = 0; k0 < K; k0 += 16) {
        #pragma unroll
        for (int i = 0; i < 8; ++i) As[kk][mm + 16 * i] = ar[i];
        #pragma unroll
        for (int i = 0; i < 4; ++i) Bs[kk][mm + 16 * i] = br[i];
        __syncthreads();
        int kn = k0 + 16;
        if (kn < K) {
            #pragma unroll
            for (int i = 0; i < 8; ++i) {
                int m = bm + mm + 16 * i;
                ar[i] = (m < M) ? A[(size_t)m * lda + kn + kk] : 0.f;
            }
            #pragma unroll
            for (int i = 0; i < 4; ++i) {
                int n = bn + mm + 16 * i;
                br[i] = (n < N) ? (sumB ? (B[(size_t)n * ldb + kn + kk]
                                           + B[(size_t)n * ldb + DD + kn + kk])
                                        : B[(size_t)n * ldb + kn + kk]) : 0.f;
            }
        }
        #pragma unroll
        for (int kq = 0; kq < 16; ++kq) {
            float a[8], b[4];
            #pragma unroll
            for (int i = 0; i < 8; ++i) a[i] = As[kq][ty * 8 + i];
            #pragma unroll
            for (int j = 0; j < 4; ++j) b[j] = Bs[kq][tx * 4 + j];
            #pragma unroll
            for (int i = 0; i < 8; ++i)
                #pragma unroll
                for (int j = 0; j < 4; ++j) acc[i][j] += a[i] * b[j];
        }
        __syncthreads();
    }
    #pragma unroll
    for (int i = 0; i < 8; ++i) {
        int m = bm + ty * 8 + i;
        if (m >= M) continue;
        #pragma unroll
        for (int j = 0; j < 4; ++j) {
            int n = bn + tx * 4 + j;
            if (n >= N) continue;
            C[(size_t)m * ldc + n] = acc[i][j] + (bias ? bias[n] : 0.f);
        }
    }
}

// ======== single prep launch: M2 + duals(+wsum folded) + mb + meta + zeroing ========
// widx   0..127: M2 = matrix . fc_w (NN 64x64 tile, K=1024)
// widx 128..559: Aq/Dq dual (z = w>=216; 9x24 tiles 128x64)
// widx 560..607: Bqa/Cqa dual (z = w>=24)
// widx 608..611: mb = matrix . fc_b
// widx 612..661: meta (q/qa/pid; creg partial -> dedicated slot, no atomic, no zero)
// widx 662..677: zero hA[2][64][512]
// widx 678:      zero W[0..1055] (acc + cells + done ctr)
__global__ __launch_bounds__(256) void prep_all(
    const float* __restrict__ q_emb, const float* __restrict__ q_emb_diff,
    const float* __restrict__ qa_emb, const float* __restrict__ qa_emb_diff,
    const float* __restrict__ w_ih, const float* __restrict__ b_ih,
    float* __restrict__ Aq, float* __restrict__ Dq,
    float* __restrict__ Bqa, float* __restrict__ Cqa,
    const float* __restrict__ matrix, const float* __restrict__ fc_w,
    const float* __restrict__ fc_b, float* __restrict__ M2, float* __restrict__ mb,
    const int* __restrict__ q_data, const int* __restrict__ qa_data,
    const int* __restrict__ pid_data, const float* __restrict__ diff_parm,
    int* __restrict__ qint, int* __restrict__ qaint, float* __restrict__ pidf,
    float* __restrict__ cregs, float* __restrict__ hA, float* __restrict__ Wbase)
{
    __shared__ float As[16][129];
    __shared__ float Bs[16][65];
    __shared__ float sm[4];
    const int tid = threadIdx.x;
    const int widx = blockIdx.x;

    if (widx < 128) {
        // M2 64x64 NN tile, K=1024
        const int bm = (widx >> 3) * 64, bn = (widx & 7) * 64;
        const int kk = tid & 15, mm = tid >> 4;
        const int nb = tid & 63, kb2 = tid >> 6;
        const int tx = tid & 15, ty = tid >> 4;
        float acc[4][4] = {};
        for (int k0 = 0; k0 < QQ; k0 += 16) {
            if (k0) __syncthreads();
            #pragma unroll
            for (int i = 0; i < 4; ++i)
                As[kk][mm + 16 * i] = matrix[(size_t)(bm + mm + 16 * i) * QQ + k0 + kk];
            #pragma unroll
            for (int i = 0; i < 4; ++i)
                Bs[kb2 + 4 * i][nb] = fc_w[(size_t)(k0 + kb2 + 4 * i) * HH + bn + nb];
            __syncthreads();
            #pragma unroll
            for (int kq = 0; kq < 16; ++kq) {
                float a[4], b[4];
                #pragma unroll
                for (int i = 0; i < 4; ++i) a[i] = As[kq][ty * 4 + i];
                #pragma unroll
                for (int j = 0; j < 4; ++j) b[j] = Bs[kq][tx * 4 + j];
                #pragma unroll
                for (int i = 0; i < 4; ++i)
                    #pragma unroll
                    for (int j = 0; j < 4; ++j) acc[i][j] += a[i] * b[j];
            }
        }
        #pragma unroll
        for (int i = 0; i < 4; ++i)
            #pragma unroll
            for (int j = 0; j < 4; ++j)
                M2[(size_t)(bm + ty * 4 + i) * HH + bn + tx * 4 + j] = acc[i][j];
        return;
    }
    if (widx < 560) {
        const int w2 = widx - 128;
        const int z = w2 >= 216;
        const int w3 = z ? w2 - 216 : w2;
        const int bm = (w3 / 24) * 128, bn = (w3 % 24) * 64;
        // z=0: Aq = q_emb . (W1+W2)^T (wsum folded); z=1: Dq = q_emb_diff . W2^T
        gemm_nt_body(z ? q_emb_diff : q_emb, DD,
                     z ? (w_ih + DD) : w_ih, 2 * DD,
                     z ? Dq : Aq, G3, NQ + 1, G3, DD,
                     nullptr, bm, bn, tid, !z, As, Bs);
        return;
    }
    if (widx < 608) {
        const int w2 = widx - 560;
        const int z = w2 >= 24;
        const int bn = (z ? w2 - 24 : w2) * 64;
        gemm_nt_body(z ? qa_emb_diff : qa_emb, DD,
                     w_ih, 2 * DD,
                     z ? Cqa : Bqa, G3, 2, G3, DD,
                     z ? nullptr : b_ih, 0, bn, tid, false, As, Bs);
        return;
    }
    if (widx < 612) {
        // mb rows: 4 blocks x 4 waves x 64 rows
        const int wv2 = tid >> 6, lane2 = tid & 63;
        const int kb = (widx - 608) * 256 + wv2 * 64;
        for (int i = 0; i < 64; ++i) {
            const float* mrow = matrix + (size_t)(kb + i) * QQ;
            float sacc = 0.f;
            #pragma unroll
            for (int j = 0; j < 16; ++j)
                sacc += mrow[lane2 + 64 * j] * fc_b[lane2 + 64 * j];
            sacc = wave_sum64(sacc);
            if (lane2 == 0) mb[kb + i] = sacc;
        }
        return;
    }
    if (widx < 662) {
        // meta; creg partial goes to a per-block slot (no atomic, slot fully written)
        int r = (widx - 612) * 256 + tid;
        float pp = 0.f;
        if (r < BL) {
            int q = q_data[r];
            qint[r] = q;
            qaint[r] = (qa_data[r] - q) / NQ;
            float pid = diff_parm[pid_data[r]];
            pidf[r] = pid;
            pp = pid * pid;
        }
        pp = wave_sum64(pp);
        int lane = tid & 63, w = tid >> 6;
        if (lane == 0) sm[w] = pp;
        __syncthreads();
        if (tid == 0) cregs[widx - 612] = sm[0] + sm[1] + sm[2] + sm[3];
        return;
    }
    if (widx < 678) {
        // zero hA (2*64*512 = 16 blocks x 4096 floats)
        float* dst = hA + (size_t)(widx - 662) * 4096 + tid;
        #pragma unroll
        for (int i = 0; i < 16; ++i) dst[i * 256] = 0.f;
        return;
    }
    // widx == 678: zero acc + cells + done ctr (W[0..1055])
    for (int i = tid; i < 1056; i += 256) Wbase[i] = 0.f;
}

// ======= persistent GRU: 2-barrier loop (per-wave poll) + fused mval + parallel tail ======
// 256 blocks = 8 bg x 32 ug; block = 8 batches x 16 units; weights in regs; per-wave
// LLC h staging; tid<128 epilogue; in-chain xg gather; meta in LDS; wave-2 M2 prefetch.
// Changes vs R10 (890us):
//  (1) TOP BARRIER DELETED: every wave polls the 32 cells itself (s_sleep(2) backoff).
//      Safe: each block's OWN cell (stored after its sync2) is in the poll set, so a
//      wave passing the poll proves its own block's epilogue readers finished -> hs/part
//      overwrite is race-free without the barrier. 2 barriers/step instead of 3.
//  (2) tail DINA scan PARALLELIZED: guess[i] is read only when us (then unchanged) and
//      written only when !us (no read); dually for slip. So ng/ns at step t depend only
//      on the most recent prior same-q step with the right us flag -> per-t backward
//      scan, fully parallel (bit-identical to the serial recurrence).
//  (3) creg from 50 prep-written slots, summed by the last finisher (memset deleted).
__global__ __launch_bounds__(512) void gru_persist(
    const float* __restrict__ Aq,      // [1025][1536]
    const float* __restrict__ Dq,      // [1025][1536]
    const float* __restrict__ Bqa,     // [2][1536]  (includes b_ih)
    const float* __restrict__ Cqa,     // [2][1536]
    const int* __restrict__ qint,      // [B][L]
    const int* __restrict__ qaint,     // [B][L]
    const float* __restrict__ pidf,    // [B][L]
    const float* __restrict__ w_hh,    // [1536][512]
    const float* __restrict__ b_hh,    // [1536]
    float* __restrict__ hA,            // [2][64][512]  (batch-major)
    const float* __restrict__ M2,      // [1024][512]
    const float* __restrict__ mbv,     // [1024]
    unsigned int* __restrict__ cells,  // 256 cells, 16B apart; [1021]=done ctr
    const float* __restrict__ target,  // [B][L]
    float* __restrict__ out,           // [1 + BL + 1]
    float* __restrict__ acc_g,         // [1]=mse [2]=cnt
    const float* __restrict__ cregs)   // [50] creg partials
{
    __shared__ float hs[8][512];          // per-wave staged h slice: [wave][b*64 + swz(col)]
    __shared__ float part[8][3][16][8];   // wave partials [wave][gate][unit][b(rotated)]
    __shared__ float bqs[2][3][16];       // Bqa slice for this block's 16 units
    __shared__ float cqs[2][3][16];       // Cqa slice
    __shared__ int smq[8][200];           // per-batch meta, whole sequence
    __shared__ int smqa[8][200];
    __shared__ float smp[8][200];
    __shared__ float mvbuf[LL];           // fused-mval ring (blocks ug<8)

    const int tid = threadIdx.x;
    const int bid = blockIdx.x;
    const int bg = bid >> 5;              // batch group 0..7 (8 batches)
    const int ug = bid & 31;
    const int j0 = ug * 16;               // first unit of this block
    const int wv = tid >> 6;              // 0..7 k-slice (64 k each)
    const int lane = tid & 63;
    const int g = lane >> 2;              // unit offset 0..15
    const int s = lane & 3;               // k sub-slice 0..3

    // ---- one-time LDS preloads: Bqa/Cqa slices + full meta sequence
    if (tid < 96) {
        const int qa = tid / 48, rem = tid - qa * 48;
        const int gate = rem >> 4, u = rem & 15;
        bqs[qa][gate][u] = Bqa[(size_t)qa * G3 + gate * HH + j0 + u];
        cqs[qa][gate][u] = Cqa[(size_t)qa * G3 + gate * HH + j0 + u];
    }
    for (int i = tid; i < 8 * LL; i += 512) {
        const int c = i / LL, tt = i - c * LL;
        const int col = bg * 8 + c;
        smq[c][tt] = qint[col * LL + tt];
        smqa[c][tt] = qaint[col * LL + tt];
        smp[c][tt] = pidf[col * LL + tt];
    }

    // ---- w_hh fragment in registers: 3 gates x 4 q x f32x4 = 48 floats/lane
    f32x4 ws4[3][4];
    #pragma unroll
    for (int gate = 0; gate < 3; ++gate)
        #pragma unroll
        for (int q = 0; q < 4; ++q)
            ws4[gate][q] = *(const f32x4*)&w_hh[
                (size_t)(gate * HH + j0 + g) * HH + wv * 64 + q * 16 + s * 4];

    // epilogue mapping (tid<128): unit eu, batch eb
    const int eu = tid >> 3;              // 0..15 when tid<128
    const int eb = tid & 7;
    float bhr = 0.f, bhz = 0.f, bhn = 0.f;
    if (tid < 128) {
        bhr = b_hh[j0 + eu];
        bhz = b_hh[HH + j0 + eu];
        bhn = b_hh[2 * HH + j0 + eu];
    }

    // staging split: lane's two 16B chunks of the wave's [8 b][64 k] slice
    const int b0 = lane >> 4;             // rows b0 and b0+4
    const int c0 = (lane & 15) * 4;       // col within k-slice

    __syncthreads();                      // bqs/cqs/meta visible

    for (int t = 0; t < LL; ++t) {
        // xg gather (waves 0-1; L3-resident tables; drained at the stage wait)
        float xr = 0.f, xz = 0.f, xn = 0.f;
        if (tid < 128) {
            const int q = smq[eb][t];
            const int qa = smqa[eb][t];
            const float pid = smp[eb][t];
            const float* aq = Aq + (size_t)q * G3 + j0 + eu;
            const float* dq = Dq + (size_t)q * G3 + j0 + eu;
            float ar_ = aq[0], az_ = aq[HH], an_ = aq[2 * HH];
            float dr_ = dq[0], dz_ = dq[HH], dn_ = dq[2 * HH];
            xr = ar_ + bqs[qa][0][eu] + pid * (cqs[qa][0][eu] + dr_);
            xz = az_ + bqs[qa][1][eu] + pid * (cqs[qa][1][eu] + dz_);
            xn = an_ + bqs[qa][2][eu] + pid * (cqs[qa][2][eu] + dn_);
        }
        // wave-2 (ug<8): prefetch M2 row + mb for mval[t-1] (drains under the poll)
        f32x4 m2a = {0.f, 0.f, 0.f, 0.f}, m2b = {0.f, 0.f, 0.f, 0.f};
        float mbq = 0.f;
        if (wv == 2 && ug < 8 && t >= 1) {
            const int q = smq[ug][t - 1] - 1;
            const float* m2r = M2 + (size_t)q * HH + lane * 8;
            m2a = *(const f32x4*)m2r;
            m2b = *(const f32x4*)(m2r + 4);
            mbq = mbv[q];
        }
        // EVERY wave polls the 32 producers (own block's cell included -> ordering)
        if (t) {
            const unsigned want = (unsigned)t;
            for (;;) {
                unsigned v = want;
                if (lane < 32)
                    v = __hip_atomic_load(&cells[(bg * 32 + lane) * 4],
                                          __ATOMIC_RELAXED, __HIP_MEMORY_SCOPE_AGENT);
                if (__all((int)(v >= want))) break;
                __builtin_amdgcn_s_sleep(2);
            }
        }

        // ---- stage h[t&1] slice (coherent LLC loads, dense 1KB/wave/inst)
        {
            const float* hcur = hA + (size_t)(t & 1) * (HH * BB);
            const float* p0 = hcur + (size_t)(bg * 8 + b0) * HH + wv * 64 + c0;
            f32x4 va = llc_load4(p0);
            f32x4 vb = llc_load4(p0 + 4 * HH);
            llc_wait2(va, vb);
            *(f32x4*)&hs[wv][b0 * 64 + ((c0 + 8 * b0) & 63)] = va;
            *(f32x4*)&hs[wv][(b0 + 4) * 64 + ((c0 + 8 * b0 + 32) & 63)] = vb;
        }

        // ---- FMA: per-lane ds_read_b128 + 384 v_fma
        float acc[3][8];
        #pragma unroll
        for (int gate = 0; gate < 3; ++gate) {
            #pragma unroll
            for (int b = 0; b < 8; ++b) acc[gate][b] = 0.f;
        }
        #pragma unroll
        for (int q = 0; q < 4; ++q) {
            const int cb = q * 16 + s * 4;
            #pragma unroll
            for (int b = 0; b < 8; ++b) {
                f32x4 h4 = *(const f32x4*)&hs[wv][b * 64 + ((cb + 8 * b) & 63)];
                #pragma unroll
                for (int gate = 0; gate < 3; ++gate) {
                    acc[gate][b] += ws4[gate][q].x * h4.x + ws4[gate][q].y * h4.y
                                  + ws4[gate][q].z * h4.z + ws4[gate][q].w * h4.w;
                }
            }
        }

        // k-reduce across the 4 s-lanes of each quad (VALU DPP)
        #pragma unroll
        for (int gate = 0; gate < 3; ++gate)
            #pragma unroll
            for (int b = 0; b < 8; ++b)
                acc[gate][b] = quad_sum(acc[gate][b]);

        // s-lane s (<3) writes gate s partials, columns rotated to spread banks.
        if (s < 3) {
            const int rot = (2 * ((g >> 2) + s)) & 7;
            #pragma unroll
            for (int hp = 0; hp < 4; ++hp) {
                const int b = hp * 2;
                float e0 = (s == 0) ? acc[0][b]     : (s == 1) ? acc[1][b]     : acc[2][b];
                float e1 = (s == 0) ? acc[0][b + 1] : (s == 1) ? acc[1][b + 1] : acc[2][b + 1];
                const int bp = (b + rot) & 7;
                *(float2*)&part[wv][s][g][bp] = make_float2(e0, e1);
            }
        }
        __syncthreads();   // sync1: partials + hs stable

        // ---- fused mval (wave 2, ug<8): prefetched M2 regs + hs -> LDS ring
        if (wv == 2 && ug < 8 && t >= 1) {
            float sacc = 0.f;
            #pragma unroll
            for (int j = 0; j < 8; ++j) {
                const int k = lane * 8 + j;
                const float hv = hs[k >> 6][ug * 64 + (((k & 63) + 8 * ug) & 63)];
                const float mvw = (j == 0) ? m2a.x : (j == 1) ? m2a.y : (j == 2) ? m2a.z
                                : (j == 3) ? m2a.w : (j == 4) ? m2b.x : (j == 5) ? m2b.y
                                : (j == 6) ? m2b.z : m2b.w;
                sacc += hv * mvw;
            }
            sacc = wave_sum64(sacc);
            if (lane == 0) {
                float sv = sacc + mbq;
                mvbuf[t - 1] = (sv >= 0.4f) ? 1.0f : sv;
            }
        }

        // ---- 8-wave reduce + gates + h store (tid<128: 16 units x 8 batches)
        if (tid < 128) {
            const int rb = eu >> 2;
            const int bp0 = (eb + 2 * (rb + 0)) & 7;
            const int bp1 = (eb + 2 * (rb + 1)) & 7;
            const int bp2 = (eb + 2 * (rb + 2)) & 7;
            float sg0 = 0.f, sg1 = 0.f, sg2 = 0.f;
            #pragma unroll
            for (int w = 0; w < 8; ++w) {
                sg0 += part[w][0][eu][bp0];
                sg1 += part[w][1][eu][bp1];
                sg2 += part[w][2][eu][bp2];
            }
            const int ku = j0 + eu;
            float hprev = hs[ku >> 6][eb * 64 + (((ku & 63) + 8 * eb) & 63)];
            float rg = 1.f / (1.f + expf(-(xr + sg0 + bhr)));
            float zg = 1.f / (1.f + expf(-(xz + sg1 + bhz)));
            float ng = tanhf(xn + rg * (sg2 + bhn));
            float hn = (1.f - zg) * ng + zg * hprev;
            llc_store1(hA + (size_t)((t + 1) & 1) * (HH * BB)
                          + (size_t)(bg * 8 + eb) * HH + ku, hn);
            asm volatile("s_waitcnt vmcnt(0)" ::: "memory");
        }
        __syncthreads();   // sync2: epilogue h-stores drained; hs/part reusable
        if (tid == 0)
            __hip_atomic_store(&cells[bid * 4], (unsigned)(t + 1),
                               __ATOMIC_RELAXED, __HIP_MEMORY_SCOPE_AGENT);
    }

    // ================= tail: blocks ug<8 (one per batch) only =================
    if (ug >= 8) return;
    // poll gen LL, stage h_{LL-1}, compute mval[LL-1]
    if (tid < 64) {
        const unsigned want = (unsigned)LL;
        for (;;) {
            unsigned v = want;
            if (lane < 32)
                v = __hip_atomic_load(&cells[(bg * 32 + lane) * 4],
                                      __ATOMIC_RELAXED, __HIP_MEMORY_SCOPE_AGENT);
            if (__all((int)(v >= want))) break;
            __builtin_amdgcn_s_sleep(2);
        }
    }
    __syncthreads();
    {
        const float* hcur = hA + (size_t)(LL & 1) * (HH * BB);
        const float* p0 = hcur + (size_t)(bg * 8 + b0) * HH + wv * 64 + c0;
        f32x4 va = llc_load4(p0);
        f32x4 vb = llc_load4(p0 + 4 * HH);
        llc_wait2(va, vb);
        *(f32x4*)&hs[wv][b0 * 64 + ((c0 + 8 * b0) & 63)] = va;
        *(f32x4*)&hs[wv][(b0 + 4) * 64 + ((c0 + 8 * b0 + 32) & 63)] = vb;
    }
    __syncthreads();
    if (wv == 2) {
        const int q = smq[ug][LL - 1] - 1;
        const float* m2r = M2 + (size_t)q * HH + lane * 8;
        f32x4 ma = *(const f32x4*)m2r;
        f32x4 mc4 = *(const f32x4*)(m2r + 4);
        float sacc = 0.f;
        #pragma unroll
        for (int j = 0; j < 8; ++j) {
            const int k = lane * 8 + j;
            const float hv = hs[k >> 6][ug * 64 + (((k & 63) + 8 * ug) & 63)];
            const float mvw = (j == 0) ? ma.x : (j == 1) ? ma.y : (j == 2) ? ma.z
                            : (j == 3) ? ma.w : (j == 4) ? mc4.x : (j == 5) ? mc4.y
                            : (j == 6) ? mc4.z : mc4.w;
            sacc += hv * mvw;
        }
        sacc = wave_sum64(sacc);
        if (lane == 0) {
            float sv = sacc + mbv[q];
            mvbuf[LL - 1] = (sv >= 0.4f) ? 1.0f : sv;
        }
    }
    __syncthreads();

    // ---- fused stats + PARALLEL DINA + loss for batch bq (all LDS-resident)
    const int bq = bg * 8 + ug;
    float* preds_l = &hs[4][0];        // 200 floats (aliases dead hs)
    float* s_mc = &part[0][0][0][0];   // stats (alias dead part)
    float* s_mi = s_mc + 256;
    float* s_nmc = s_mc + 512;
    float* s_aa = s_mc + 768;
    float* sred = &bqs[0][0][0];       // 8 floats (aliases dead bqs)
    float* cred = sred + 8;
    if (tid < LL) {
        const int qt = smq[ug][tid];
        float smc = 0.f, smi = 0.f, snmc = 0.f, saa = 0.f;
        for (int k = 0; k <= tid; ++k) {
            if (smq[ug][k] == qt) {
                saa += 1.f;
                if (k < tid) {
                    float mk = (mvbuf[k] == 1.f) ? 1.f : 0.f;
                    float nk = (mvbuf[k] == 0.f) ? 1.f : 0.f;
                    float a1 = (smqa[ug][k] == 1) ? 1.f : 0.f;
                    smc += a1 * mk;
                    smi += (1.f - a1) * mk;
                    snmc += (1.f - a1) * nk;
                }
            }
        }
        s_mc[tid] = smc;
        s_mi[tid] = smi;
        s_nmc[tid] = snmc;
        s_aa[tid] = saa;
    }
    __syncthreads();
    // DINA, parallel per t: ng/ns depend only on the most recent prior same-q
    // step with the matching us flag (guess written only when !us; slip only when us).
    if (tid < LL) {
        const int t = tid;
        const int qt = smq[ug][t];
        const float m = mvbuf[t];
        const int qa = smqa[ug][t];
        const bool ust = (m == 1.f) && (qa == 0);
        float gval = 0.f, sval = 0.f;   // init guess/slip = 0
        bool gf = false, sf = false;
        for (int k = t - 1; k >= 0; --k) {
            if (gf && sf) break;
            if (smq[ug][k] != qt) continue;
            const float mk = mvbuf[k];
            const int qak = smqa[ug][k];
            const bool usk = (mk == 1.f) && (qak == 0);
            if (usk) {
                if (!sf) { sval = s_mi[k] / s_aa[k]; sf = true; }
            } else {
                if (!gf) {
                    gval = (mk == 1.f) ? s_mc[k] / s_aa[k]
                         : ((qak == 0) ? 1.f - s_nmc[k] / s_aa[k] : s_nmc[k] / s_aa[k]);
                    gf = true;
                }
            }
        }
        const float g_upd = (m == 1.f) ? s_mc[t] / s_aa[t]
                          : ((qa == 0) ? 1.f - s_nmc[t] / s_aa[t] : s_nmc[t] / s_aa[t]);
        const float ng = ust ? gval : g_upd;
        const float ns = ust ? s_mi[t] / s_aa[t] : sval;
        preds_l[t] = (1.f - ns) * (m * ng + (1.f - ns) * (1.f - m));
    }
    __syncthreads();
    if (tid < 256) {
        float lm = 0.f, lc = 0.f;
        if (tid < LL) {
            const float p = preds_l[tid];
            const float lab = target[bq * LL + tid];
            const float msk = (lab > -0.9f) ? 1.f : 0.f;
            const float d = p - lab;
            lm = d * d * msk;
            lc = msk;
            out[1 + bq * LL + tid] = 1.f / (1.f + expf(-p));
        }
        lm = wave_sum64(lm);
        lc = wave_sum64(lc);
        if (lane == 0) { sred[wv] = lm; cred[wv] = lc; }
    }
    __syncthreads();
    if (tid == 0) {
        atomicAdd(&acc_g[1], sred[0] + sred[1] + sred[2] + sred[3]);
        atomicAdd(&acc_g[2], cred[0] + cred[1] + cred[2] + cred[3]);
        const unsigned old = __hip_atomic_fetch_add(&cells[1021], 1u,
                                                    __ATOMIC_ACQ_REL,
                                                    __HIP_MEMORY_SCOPE_AGENT);
        if (old == 63) {
            float cr = 0.f;
            for (int i = 0; i < 50; ++i) cr += cregs[i];
            float a1 = __hip_atomic_load(&acc_g[1], __ATOMIC_RELAXED, __HIP_MEMORY_SCOPE_AGENT);
            float a2 = __hip_atomic_load(&acc_g[2], __ATOMIC_RELAXED, __HIP_MEMORY_SCOPE_AGENT);
            out[0] = a1 + cr * 1e-5f;
            out[1 + BL] = a2;
        }
    }
}

extern "C" void kernel_launch(void* const* d_in, const int* in_sizes, int n_in,
                              void* d_out, int out_size, void* d_ws, size_t ws_size,
                              hipStream_t stream) {
    const int* q_data = (const int*)d_in[0];
    const int* qa_data = (const int*)d_in[1];
    const int* pid_data = (const int*)d_in[2];
    const float* matrix = (const float*)d_in[3];
    const float* target = (const float*)d_in[4];
    const float* q_emb = (const float*)d_in[5];
    const float* qa_emb = (const float*)d_in[6];
    const float* q_emb_diff = (const float*)d_in[7];
    const float* qa_emb_diff = (const float*)d_in[8];
    const float* diff_parm = (const float*)d_in[9];
    const float* w_ih = (const float*)d_in[10];
    const float* w_hh = (const float*)d_in[11];
    const float* b_ih = (const float*)d_in[12];
    const float* b_hh = (const float*)d_in[13];
    const float* fc_w = (const float*)d_in[14];
    const float* fc_b = (const float*)d_in[15];
    float* out = (float*)d_out;
    float* W = (float*)d_ws;

    float* acc = W + OFF_ACC;
    unsigned int* cells = (unsigned int*)(W + OFF_CELLS);
    float* hA = W + OFF_HA;
    float* Aq = W + OFF_AQ;
    float* Dq = W + OFF_DQ;
    float* Bqa = W + OFF_BQA;
    float* Cqa = W + OFF_CQA;
    float* cregs = W + OFF_CREGS;
    float* M2 = W + OFF_M2;
    float* mb = W + OFF_MB;
    int* qint = (int*)(W + OFF_QINT);
    int* qaint = (int*)(W + OFF_QAINT);
    float* pidf = W + OFF_PIDF;

    // single prep launch (M2 first = LPT; duals; mb; meta->creg slots; hA + acc/cells zero)
    prep_all<<<679, 256, 0, stream>>>(
        q_emb, q_emb_diff, qa_emb, qa_emb_diff, w_ih, b_ih,
        Aq, Dq, Bqa, Cqa, matrix, fc_w, fc_b, M2, mb,
        q_data, qa_data, pid_data, diff_parm, qint, qaint, pidf, cregs, hA, W);

    // GRU: 2-barrier loop + fused mval + parallel tail stats/dina/loss/final
    gru_persist<<<GBLK, 512, 0, stream>>>(Aq, Dq, Bqa, Cqa, qint, qaint, pidf,
                                          w_hh, b_hh, hA, M2, mb, cells,
                                          target, out, acc, cregs);
}

// Round 12
// 978.376 us; speedup vs baseline: 1.1616x; 1.1616x over previous
//
#include <hip/hip_runtime.h>
#include <hip/hip_bf16.h>
#include <math.h>

// Problem constants
#define BB 64
#define LL 200
#define NQ 1024
#define DD 256
#define HH 512
#define QQ 1024
#define G3 1536   // 3*H
#define BL 12800  // B*L
#define GBLK 256  // persistent GRU grid: 1 block/CU

// ---------------- workspace layout (in floats) ----------------
#define OFF_ACC   ((size_t)0)                    // [1]=mse [2]=maskcnt
#define OFF_CELLS ((size_t)16)                   // 256 cells, 16B apart + done ctr (1024 uints)
#define OFF_HA    ((size_t)1056)                 // hA[2][64][512] batch-major
#define OFF_AQ    (OFF_HA + 65536)               // 1025*1536
#define OFF_DQ    (OFF_AQ + 1574400)
#define OFF_BQA   (OFF_DQ + 1574400)             // 2*1536
#define OFF_CQA   (OFF_BQA + 3072)
#define OFF_CREGS (OFF_CQA + 3072)               // 50 creg partial slots
#define OFF_FCWT  (OFF_CREGS + 393216)           // (unused)
#define OFF_M2    (OFF_FCWT + 524288)            // 1024*512
#define OFF_MB    (OFF_M2 + 524288)              // 1024
#define OFF_QINT  (OFF_MB + 1024)                // 12800 ints [B][L]
#define OFF_QAINT (OFF_QINT + 12800)
#define OFF_PIDF  (OFF_QAINT + 12800)

typedef float f32x4 __attribute__((ext_vector_type(4)));

__device__ __forceinline__ float wave_sum64(float v) {
    #pragma unroll
    for (int o = 32; o > 0; o >>= 1) v += __shfl_down(v, o, 64);
    return v;
}

// LLC-coherent (bypass L1/L2) ops
__device__ __forceinline__ f32x4 llc_load4(const float* p) {
    f32x4 v;
    asm volatile("global_load_dwordx4 %0, %1, off sc0 sc1" : "=v"(v) : "v"(p));
    return v;
}
__device__ __forceinline__ void llc_wait2(f32x4& a, f32x4& b) {
    asm volatile("s_waitcnt vmcnt(0)" : "+v"(a), "+v"(b));
}
__device__ __forceinline__ void llc_store1(float* p, float v) {
    asm volatile("global_store_dword %0, %1, off sc0 sc1" :: "v"(p), "v"(v) : "memory");
}

// quad (4-lane) butterfly sum via DPP quad_perm (VALU pipe, not LDS)
__device__ __forceinline__ float quad_sum(float v) {
    float t1 = __int_as_float(__builtin_amdgcn_update_dpp(
        0, __float_as_int(v), 0xB1, 0xF, 0xF, true));   // quad_perm xor1
    v += t1;
    float t2 = __int_as_float(__builtin_amdgcn_update_dpp(
        0, __float_as_int(v), 0x4E, 0xF, 0xF, true));   // quad_perm xor2
    return v + t2;
}

// -------- 128x64 NT GEMM tile body (verified compute; optional B = sum of halves) ----
__device__ __forceinline__ void gemm_nt_body(
    const float* __restrict__ A, int lda, const float* __restrict__ B, int ldb,
    float* __restrict__ C, int ldc, int M, int N, int K,
    const float* __restrict__ bias, int bm, int bn, int tid, bool sumB,
    float (*As)[129], float (*Bs)[65])
{
    const int tx = tid & 15, ty = tid >> 4;
    const int mm = tid >> 4, kk = tid & 15;
    float acc[8][4] = {};
    float ar[8], br[4];
    #pragma unroll
    for (int i = 0; i < 8; ++i) {
        int m = bm + mm + 16 * i;
        ar[i] = (m < M) ? A[(size_t)m * lda + kk] : 0.f;
    }
    #pragma unroll
    for (int i = 0; i < 4; ++i) {
        int n = bn + mm + 16 * i;
        br[i] = (n < N) ? (sumB ? (B[(size_t)n * ldb + kk] + B[(size_t)n * ldb + DD + kk])
                                : B[(size_t)n * ldb + kk]) : 0.f;
    }
    for (int k0 = 0; k0 < K; k0 += 16) {
        #pragma unroll
        for (int i = 0; i < 8; ++i) As[kk][mm + 16 * i] = ar[i];
        #pragma unroll
        for (int i = 0; i < 4; ++i) Bs[kk][mm + 16 * i] = br[i];
        __syncthreads();
        int kn = k0 + 16;
        if (kn < K) {
            #pragma unroll
            for (int i = 0; i < 8; ++i) {
                int m = bm + mm + 16 * i;
                ar[i] = (m < M) ? A[(size_t)m * lda + kn + kk] : 0.f;
            }
            #pragma unroll
            for (int i = 0; i < 4; ++i) {
                int n = bn + mm + 16 * i;
                br[i] = (n < N) ? (sumB ? (B[(size_t)n * ldb + kn + kk]
                                           + B[(size_t)n * ldb + DD + kn + kk])
                                        : B[(size_t)n * ldb + kn + kk]) : 0.f;
            }
        }
        #pragma unroll
        for (int kq = 0; kq < 16; ++kq) {
            float a[8], b[4];
            #pragma unroll
            for (int i = 0; i < 8; ++i) a[i] = As[kq][ty * 8 + i];
            #pragma unroll
            for (int j = 0; j < 4; ++j) b[j] = Bs[kq][tx * 4 + j];
            #pragma unroll
            for (int i = 0; i < 8; ++i)
                #pragma unroll
                for (int j = 0; j < 4; ++j) acc[i][j] += a[i] * b[j];
        }
        __syncthreads();
    }
    #pragma unroll
    for (int i = 0; i < 8; ++i) {
        int m = bm + ty * 8 + i;
        if (m >= M) continue;
        #pragma unroll
        for (int j = 0; j < 4; ++j) {
            int n = bn + tx * 4 + j;
            if (n >= N) continue;
            C[(size_t)m * ldc + n] = acc[i][j] + (bias ? bias[n] : 0.f);
        }
    }
}

// ======== single prep launch: M2 + duals(+wsum folded) + mb + meta + zeroing ========
__global__ __launch_bounds__(256) void prep_all(
    const float* __restrict__ q_emb, const float* __restrict__ q_emb_diff,
    const float* __restrict__ qa_emb, const float* __restrict__ qa_emb_diff,
    const float* __restrict__ w_ih, const float* __restrict__ b_ih,
    float* __restrict__ Aq, float* __restrict__ Dq,
    float* __restrict__ Bqa, float* __restrict__ Cqa,
    const float* __restrict__ matrix, const float* __restrict__ fc_w,
    const float* __restrict__ fc_b, float* __restrict__ M2, float* __restrict__ mb,
    const int* __restrict__ q_data, const int* __restrict__ qa_data,
    const int* __restrict__ pid_data, const float* __restrict__ diff_parm,
    int* __restrict__ qint, int* __restrict__ qaint, float* __restrict__ pidf,
    float* __restrict__ cregs, float* __restrict__ hA, float* __restrict__ Wbase)
{
    __shared__ float As[16][129];
    __shared__ float Bs[16][65];
    __shared__ float sm[4];
    const int tid = threadIdx.x;
    const int widx = blockIdx.x;

    if (widx < 128) {
        // M2 64x64 NN tile, K=1024
        const int bm = (widx >> 3) * 64, bn = (widx & 7) * 64;
        const int kk = tid & 15, mm = tid >> 4;
        const int nb = tid & 63, kb2 = tid >> 6;
        const int tx = tid & 15, ty = tid >> 4;
        float acc[4][4] = {};
        for (int k0 = 0; k0 < QQ; k0 += 16) {
            if (k0) __syncthreads();
            #pragma unroll
            for (int i = 0; i < 4; ++i)
                As[kk][mm + 16 * i] = matrix[(size_t)(bm + mm + 16 * i) * QQ + k0 + kk];
            #pragma unroll
            for (int i = 0; i < 4; ++i)
                Bs[kb2 + 4 * i][nb] = fc_w[(size_t)(k0 + kb2 + 4 * i) * HH + bn + nb];
            __syncthreads();
            #pragma unroll
            for (int kq = 0; kq < 16; ++kq) {
                float a[4], b[4];
                #pragma unroll
                for (int i = 0; i < 4; ++i) a[i] = As[kq][ty * 4 + i];
                #pragma unroll
                for (int j = 0; j < 4; ++j) b[j] = Bs[kq][tx * 4 + j];
                #pragma unroll
                for (int i = 0; i < 4; ++i)
                    #pragma unroll
                    for (int j = 0; j < 4; ++j) acc[i][j] += a[i] * b[j];
            }
        }
        #pragma unroll
        for (int i = 0; i < 4; ++i)
            #pragma unroll
            for (int j = 0; j < 4; ++j)
                M2[(size_t)(bm + ty * 4 + i) * HH + bn + tx * 4 + j] = acc[i][j];
        return;
    }
    if (widx < 560) {
        const int w2 = widx - 128;
        const int z = w2 >= 216;
        const int w3 = z ? w2 - 216 : w2;
        const int bm = (w3 / 24) * 128, bn = (w3 % 24) * 64;
        // z=0: Aq = q_emb . (W1+W2)^T (wsum folded); z=1: Dq = q_emb_diff . W2^T
        gemm_nt_body(z ? q_emb_diff : q_emb, DD,
                     z ? (w_ih + DD) : w_ih, 2 * DD,
                     z ? Dq : Aq, G3, NQ + 1, G3, DD,
                     nullptr, bm, bn, tid, !z, As, Bs);
        return;
    }
    if (widx < 608) {
        const int w2 = widx - 560;
        const int z = w2 >= 24;
        const int bn = (z ? w2 - 24 : w2) * 64;
        gemm_nt_body(z ? qa_emb_diff : qa_emb, DD,
                     w_ih, 2 * DD,
                     z ? Cqa : Bqa, G3, 2, G3, DD,
                     z ? nullptr : b_ih, 0, bn, tid, false, As, Bs);
        return;
    }
    if (widx < 612) {
        // mb rows: 4 blocks x 4 waves x 64 rows
        const int wv2 = tid >> 6, lane2 = tid & 63;
        const int kb = (widx - 608) * 256 + wv2 * 64;
        for (int i = 0; i < 64; ++i) {
            const float* mrow = matrix + (size_t)(kb + i) * QQ;
            float sacc = 0.f;
            #pragma unroll
            for (int j = 0; j < 16; ++j)
                sacc += mrow[lane2 + 64 * j] * fc_b[lane2 + 64 * j];
            sacc = wave_sum64(sacc);
            if (lane2 == 0) mb[kb + i] = sacc;
        }
        return;
    }
    if (widx < 662) {
        // meta; creg partial goes to a per-block slot (no atomic, slot fully written)
        int r = (widx - 612) * 256 + tid;
        float pp = 0.f;
        if (r < BL) {
            int q = q_data[r];
            qint[r] = q;
            qaint[r] = (qa_data[r] - q) / NQ;
            float pid = diff_parm[pid_data[r]];
            pidf[r] = pid;
            pp = pid * pid;
        }
        pp = wave_sum64(pp);
        int lane = tid & 63, w = tid >> 6;
        if (lane == 0) sm[w] = pp;
        __syncthreads();
        if (tid == 0) cregs[widx - 612] = sm[0] + sm[1] + sm[2] + sm[3];
        return;
    }
    if (widx < 678) {
        // zero hA (2*64*512 = 16 blocks x 4096 floats)
        float* dst = hA + (size_t)(widx - 662) * 4096 + tid;
        #pragma unroll
        for (int i = 0; i < 16; ++i) dst[i * 256] = 0.f;
        return;
    }
    // widx == 678: zero acc + cells + done ctr (W[0..1055])
    for (int i = tid; i < 1056; i += 256) Wbase[i] = 0.f;
}

// ======= persistent GRU (R10-890 loop protocol) + fused mval + PARALLEL tail ======
// 256 blocks = 8 bg x 32 ug; block = 8 batches x 16 units; weights in regs; per-wave
// LLC h staging; 3 barriers/step; tid<128 epilogue; WAVE-0-ONLY poll (R11's per-wave
// poll cost +0.47us/step: 8 LLC poll loops replaced one cheap barrier -> reverted);
// in-chain xg gather; meta in LDS; wave-2 M2 prefetch (drains under the poll).
// Tail: parallel stats + PARALLEL DINA (last-writer-wins decomposition) + loss.
__global__ __launch_bounds__(512) void gru_persist(
    const float* __restrict__ Aq,      // [1025][1536]
    const float* __restrict__ Dq,      // [1025][1536]
    const float* __restrict__ Bqa,     // [2][1536]  (includes b_ih)
    const float* __restrict__ Cqa,     // [2][1536]
    const int* __restrict__ qint,      // [B][L]
    const int* __restrict__ qaint,     // [B][L]
    const float* __restrict__ pidf,    // [B][L]
    const float* __restrict__ w_hh,    // [1536][512]
    const float* __restrict__ b_hh,    // [1536]
    float* __restrict__ hA,            // [2][64][512]  (batch-major)
    const float* __restrict__ M2,      // [1024][512]
    const float* __restrict__ mbv,     // [1024]
    unsigned int* __restrict__ cells,  // 256 cells, 16B apart; [1021]=done ctr
    const float* __restrict__ target,  // [B][L]
    float* __restrict__ out,           // [1 + BL + 1]
    float* __restrict__ acc_g,         // [1]=mse [2]=cnt
    const float* __restrict__ cregs)   // [50] creg partials
{
    __shared__ float hs[8][512];          // per-wave staged h slice: [wave][b*64 + swz(col)]
    __shared__ float part[8][3][16][8];   // wave partials [wave][gate][unit][b(rotated)]
    __shared__ float bqs[2][3][16];       // Bqa slice for this block's 16 units
    __shared__ float cqs[2][3][16];       // Cqa slice
    __shared__ int smq[8][200];           // per-batch meta, whole sequence
    __shared__ int smqa[8][200];
    __shared__ float smp[8][200];
    __shared__ float mvbuf[LL];           // fused-mval ring (blocks ug<8)

    const int tid = threadIdx.x;
    const int bid = blockIdx.x;
    const int bg = bid >> 5;              // batch group 0..7 (8 batches)
    const int ug = bid & 31;
    const int j0 = ug * 16;               // first unit of this block
    const int wv = tid >> 6;              // 0..7 k-slice (64 k each)
    const int lane = tid & 63;
    const int g = lane >> 2;              // unit offset 0..15
    const int s = lane & 3;               // k sub-slice 0..3

    // ---- one-time LDS preloads: Bqa/Cqa slices + full meta sequence
    if (tid < 96) {
        const int qa = tid / 48, rem = tid - qa * 48;
        const int gate = rem >> 4, u = rem & 15;
        bqs[qa][gate][u] = Bqa[(size_t)qa * G3 + gate * HH + j0 + u];
        cqs[qa][gate][u] = Cqa[(size_t)qa * G3 + gate * HH + j0 + u];
    }
    for (int i = tid; i < 8 * LL; i += 512) {
        const int c = i / LL, tt = i - c * LL;
        const int col = bg * 8 + c;
        smq[c][tt] = qint[col * LL + tt];
        smqa[c][tt] = qaint[col * LL + tt];
        smp[c][tt] = pidf[col * LL + tt];
    }

    // ---- w_hh fragment in registers: 3 gates x 4 q x f32x4 = 48 floats/lane
    f32x4 ws4[3][4];
    #pragma unroll
    for (int gate = 0; gate < 3; ++gate)
        #pragma unroll
        for (int q = 0; q < 4; ++q)
            ws4[gate][q] = *(const f32x4*)&w_hh[
                (size_t)(gate * HH + j0 + g) * HH + wv * 64 + q * 16 + s * 4];

    // epilogue mapping (tid<128): unit eu, batch eb
    const int eu = tid >> 3;              // 0..15 when tid<128
    const int eb = tid & 7;
    float bhr = 0.f, bhz = 0.f, bhn = 0.f;
    if (tid < 128) {
        bhr = b_hh[j0 + eu];
        bhz = b_hh[HH + j0 + eu];
        bhn = b_hh[2 * HH + j0 + eu];
    }

    // staging split: lane's two 16B chunks of the wave's [8 b][64 k] slice
    const int b0 = lane >> 4;             // rows b0 and b0+4
    const int c0 = (lane & 15) * 4;       // col within k-slice

    __syncthreads();                      // bqs/cqs/meta visible

    for (int t = 0; t < LL; ++t) {
        // xg gather (waves 0-1; L3-resident tables; drained at the stage wait)
        float xr = 0.f, xz = 0.f, xn = 0.f;
        if (tid < 128) {
            const int q = smq[eb][t];
            const int qa = smqa[eb][t];
            const float pid = smp[eb][t];
            const float* aq = Aq + (size_t)q * G3 + j0 + eu;
            const float* dq = Dq + (size_t)q * G3 + j0 + eu;
            float ar_ = aq[0], az_ = aq[HH], an_ = aq[2 * HH];
            float dr_ = dq[0], dz_ = dq[HH], dn_ = dq[2 * HH];
            xr = ar_ + bqs[qa][0][eu] + pid * (cqs[qa][0][eu] + dr_);
            xz = az_ + bqs[qa][1][eu] + pid * (cqs[qa][1][eu] + dz_);
            xn = an_ + bqs[qa][2][eu] + pid * (cqs[qa][2][eu] + dn_);
        }
        // wave-2 (ug<8): prefetch M2 row + mb for mval[t-1] (drains under the poll)
        f32x4 m2a = {0.f, 0.f, 0.f, 0.f}, m2b = {0.f, 0.f, 0.f, 0.f};
        float mbq = 0.f;
        if (wv == 2 && ug < 8 && t >= 1) {
            const int q = smq[ug][t - 1] - 1;
            const float* m2r = M2 + (size_t)q * HH + lane * 8;
            m2a = *(const f32x4*)m2r;
            m2b = *(const f32x4*)(m2r + 4);
            mbq = mbv[q];
        }
        // wave 0 ONLY: poll the 32 producers (others wait at the cheap barrier)
        if (t && tid < 64) {
            const unsigned want = (unsigned)t;
            for (;;) {
                unsigned v = want;
                if (lane < 32)
                    v = __hip_atomic_load(&cells[(bg * 32 + lane) * 4],
                                          __ATOMIC_RELAXED, __HIP_MEMORY_SCOPE_AGENT);
                if (__all((int)(v >= want))) break;
                __builtin_amdgcn_s_sleep(2);
            }
        }
        __syncthreads();

        // ---- stage h[t&1] slice (coherent LLC loads, dense 1KB/wave/inst)
        {
            const float* hcur = hA + (size_t)(t & 1) * (HH * BB);
            const float* p0 = hcur + (size_t)(bg * 8 + b0) * HH + wv * 64 + c0;
            f32x4 va = llc_load4(p0);
            f32x4 vb = llc_load4(p0 + 4 * HH);
            llc_wait2(va, vb);
            *(f32x4*)&hs[wv][b0 * 64 + ((c0 + 8 * b0) & 63)] = va;
            *(f32x4*)&hs[wv][(b0 + 4) * 64 + ((c0 + 8 * b0 + 32) & 63)] = vb;
        }

        // ---- FMA: per-lane ds_read_b128 + 384 v_fma
        float acc[3][8];
        #pragma unroll
        for (int gate = 0; gate < 3; ++gate) {
            #pragma unroll
            for (int b = 0; b < 8; ++b) acc[gate][b] = 0.f;
        }
        #pragma unroll
        for (int q = 0; q < 4; ++q) {
            const int cb = q * 16 + s * 4;
            #pragma unroll
            for (int b = 0; b < 8; ++b) {
                f32x4 h4 = *(const f32x4*)&hs[wv][b * 64 + ((cb + 8 * b) & 63)];
                #pragma unroll
                for (int gate = 0; gate < 3; ++gate) {
                    acc[gate][b] += ws4[gate][q].x * h4.x + ws4[gate][q].y * h4.y
                                  + ws4[gate][q].z * h4.z + ws4[gate][q].w * h4.w;
                }
            }
        }

        // k-reduce across the 4 s-lanes of each quad (VALU DPP)
        #pragma unroll
        for (int gate = 0; gate < 3; ++gate)
            #pragma unroll
            for (int b = 0; b < 8; ++b)
                acc[gate][b] = quad_sum(acc[gate][b]);

        // s-lane s (<3) writes gate s partials, columns rotated to spread banks.
        if (s < 3) {
            const int rot = (2 * ((g >> 2) + s)) & 7;
            #pragma unroll
            for (int hp = 0; hp < 4; ++hp) {
                const int b = hp * 2;
                float e0 = (s == 0) ? acc[0][b]     : (s == 1) ? acc[1][b]     : acc[2][b];
                float e1 = (s == 0) ? acc[0][b + 1] : (s == 1) ? acc[1][b + 1] : acc[2][b + 1];
                const int bp = (b + rot) & 7;
                *(float2*)&part[wv][s][g][bp] = make_float2(e0, e1);
            }
        }
        __syncthreads();   // sync1: partials + hs stable

        // ---- fused mval (wave 2, ug<8): prefetched M2 regs + hs -> LDS ring
        if (wv == 2 && ug < 8 && t >= 1) {
            float sacc = 0.f;
            #pragma unroll
            for (int j = 0; j < 8; ++j) {
                const int k = lane * 8 + j;
                const float hv = hs[k >> 6][ug * 64 + (((k & 63) + 8 * ug) & 63)];
                const float mvw = (j == 0) ? m2a.x : (j == 1) ? m2a.y : (j == 2) ? m2a.z
                                : (j == 3) ? m2a.w : (j == 4) ? m2b.x : (j == 5) ? m2b.y
                                : (j == 6) ? m2b.z : m2b.w;
                sacc += hv * mvw;
            }
            sacc = wave_sum64(sacc);
            if (lane == 0) {
                float sv = sacc + mbq;
                mvbuf[t - 1] = (sv >= 0.4f) ? 1.0f : sv;
            }
        }

        // ---- 8-wave reduce + gates + h store (tid<128: 16 units x 8 batches)
        if (tid < 128) {
            const int rb = eu >> 2;
            const int bp0 = (eb + 2 * (rb + 0)) & 7;
            const int bp1 = (eb + 2 * (rb + 1)) & 7;
            const int bp2 = (eb + 2 * (rb + 2)) & 7;
            float sg0 = 0.f, sg1 = 0.f, sg2 = 0.f;
            #pragma unroll
            for (int w = 0; w < 8; ++w) {
                sg0 += part[w][0][eu][bp0];
                sg1 += part[w][1][eu][bp1];
                sg2 += part[w][2][eu][bp2];
            }
            const int ku = j0 + eu;
            float hprev = hs[ku >> 6][eb * 64 + (((ku & 63) + 8 * eb) & 63)];
            float rg = 1.f / (1.f + expf(-(xr + sg0 + bhr)));
            float zg = 1.f / (1.f + expf(-(xz + sg1 + bhz)));
            float ng = tanhf(xn + rg * (sg2 + bhn));
            float hn = (1.f - zg) * ng + zg * hprev;
            llc_store1(hA + (size_t)((t + 1) & 1) * (HH * BB)
                          + (size_t)(bg * 8 + eb) * HH + ku, hn);
            asm volatile("s_waitcnt vmcnt(0)" ::: "memory");
        }
        __syncthreads();   // sync2: epilogue h-stores drained; hs/part reusable
        if (tid == 0)
            __hip_atomic_store(&cells[bid * 4], (unsigned)(t + 1),
                               __ATOMIC_RELAXED, __HIP_MEMORY_SCOPE_AGENT);
    }

    // ================= tail: blocks ug<8 (one per batch) only =================
    if (ug >= 8) return;
    // poll gen LL, stage h_{LL-1}, compute mval[LL-1]
    if (tid < 64) {
        const unsigned want = (unsigned)LL;
        for (;;) {
            unsigned v = want;
            if (lane < 32)
                v = __hip_atomic_load(&cells[(bg * 32 + lane) * 4],
                                      __ATOMIC_RELAXED, __HIP_MEMORY_SCOPE_AGENT);
            if (__all((int)(v >= want))) break;
            __builtin_amdgcn_s_sleep(2);
        }
    }
    __syncthreads();
    {
        const float* hcur = hA + (size_t)(LL & 1) * (HH * BB);
        const float* p0 = hcur + (size_t)(bg * 8 + b0) * HH + wv * 64 + c0;
        f32x4 va = llc_load4(p0);
        f32x4 vb = llc_load4(p0 + 4 * HH);
        llc_wait2(va, vb);
        *(f32x4*)&hs[wv][b0 * 64 + ((c0 + 8 * b0) & 63)] = va;
        *(f32x4*)&hs[wv][(b0 + 4) * 64 + ((c0 + 8 * b0 + 32) & 63)] = vb;
    }
    __syncthreads();
    if (wv == 2) {
        const int q = smq[ug][LL - 1] - 1;
        const float* m2r = M2 + (size_t)q * HH + lane * 8;
        f32x4 ma = *(const f32x4*)m2r;
        f32x4 mc4 = *(const f32x4*)(m2r + 4);
        float sacc = 0.f;
        #pragma unroll
        for (int j = 0; j < 8; ++j) {
            const int k = lane * 8 + j;
            const float hv = hs[k >> 6][ug * 64 + (((k & 63) + 8 * ug) & 63)];
            const float mvw = (j == 0) ? ma.x : (j == 1) ? ma.y : (j == 2) ? ma.z
                            : (j == 3) ? ma.w : (j == 4) ? mc4.x : (j == 5) ? mc4.y
                            : (j == 6) ? mc4.z : mc4.w;
            sacc += hv * mvw;
        }
        sacc = wave_sum64(sacc);
        if (lane == 0) {
            float sv = sacc + mbv[q];
            mvbuf[LL - 1] = (sv >= 0.4f) ? 1.0f : sv;
        }
    }
    __syncthreads();

    // ---- fused stats + PARALLEL DINA + loss for batch bq (all LDS-resident)
    const int bq = bg * 8 + ug;
    float* preds_l = &hs[4][0];        // 200 floats (aliases dead hs)
    float* s_mc = &part[0][0][0][0];   // stats (alias dead part)
    float* s_mi = s_mc + 256;
    float* s_nmc = s_mc + 512;
    float* s_aa = s_mc + 768;
    float* sred = &bqs[0][0][0];       // 8 floats (aliases dead bqs)
    float* cred = sred + 8;
    if (tid < LL) {
        const int qt = smq[ug][tid];
        float smc = 0.f, smi = 0.f, snmc = 0.f, saa = 0.f;
        for (int k = 0; k <= tid; ++k) {
            if (smq[ug][k] == qt) {
                saa += 1.f;
                if (k < tid) {
                    float mk = (mvbuf[k] == 1.f) ? 1.f : 0.f;
                    float nk = (mvbuf[k] == 0.f) ? 1.f : 0.f;
                    float a1 = (smqa[ug][k] == 1) ? 1.f : 0.f;
                    smc += a1 * mk;
                    smi += (1.f - a1) * mk;
                    snmc += (1.f - a1) * nk;
                }
            }
        }
        s_mc[tid] = smc;
        s_mi[tid] = smi;
        s_nmc[tid] = snmc;
        s_aa[tid] = saa;
    }
    __syncthreads();
    // DINA, parallel per t: ng/ns depend only on the most recent prior same-q
    // step with the matching us flag (guess written only when !us; slip only when us).
    if (tid < LL) {
        const int t = tid;
        const int qt = smq[ug][t];
        const float m = mvbuf[t];
        const int qa = smqa[ug][t];
        const bool ust = (m == 1.f) && (qa == 0);
        float gval = 0.f, sval = 0.f;   // init guess/slip = 0
        bool gf = false, sf = false;
        for (int k = t - 1; k >= 0; --k) {
            if (gf && sf) break;
            if (smq[ug][k] != qt) continue;
            const float mk = mvbuf[k];
            const int qak = smqa[ug][k];
            const bool usk = (mk == 1.f) && (qak == 0);
            if (usk) {
                if (!sf) { sval = s_mi[k] / s_aa[k]; sf = true; }
            } else {
                if (!gf) {
                    gval = (mk == 1.f) ? s_mc[k] / s_aa[k]
                         : ((qak == 0) ? 1.f - s_nmc[k] / s_aa[k] : s_nmc[k] / s_aa[k]);
                    gf = true;
                }
            }
        }
        const float g_upd = (m == 1.f) ? s_mc[t] / s_aa[t]
                          : ((qa == 0) ? 1.f - s_nmc[t] / s_aa[t] : s_nmc[t] / s_aa[t]);
        const float ng = ust ? gval : g_upd;
        const float ns = ust ? s_mi[t] / s_aa[t] : sval;
        preds_l[t] = (1.f - ns) * (m * ng + (1.f - ns) * (1.f - m));
    }
    __syncthreads();
    if (tid < 256) {
        float lm = 0.f, lc = 0.f;
        if (tid < LL) {
            const float p = preds_l[tid];
            const float lab = target[bq * LL + tid];
            const float msk = (lab > -0.9f) ? 1.f : 0.f;
            const float d = p - lab;
            lm = d * d * msk;
            lc = msk;
            out[1 + bq * LL + tid] = 1.f / (1.f + expf(-p));
        }
        lm = wave_sum64(lm);
        lc = wave_sum64(lc);
        if (lane == 0) { sred[wv] = lm; cred[wv] = lc; }
    }
    __syncthreads();
    if (tid == 0) {
        atomicAdd(&acc_g[1], sred[0] + sred[1] + sred[2] + sred[3]);
        atomicAdd(&acc_g[2], cred[0] + cred[1] + cred[2] + cred[3]);
        const unsigned old = __hip_atomic_fetch_add(&cells[1021], 1u,
                                                    __ATOMIC_ACQ_REL,
                                                    __HIP_MEMORY_SCOPE_AGENT);
        if (old == 63) {
            float cr = 0.f;
            for (int i = 0; i < 50; ++i) cr += cregs[i];
            float a1 = __hip_atomic_load(&acc_g[1], __ATOMIC_RELAXED, __HIP_MEMORY_SCOPE_AGENT);
            float a2 = __hip_atomic_load(&acc_g[2], __ATOMIC_RELAXED, __HIP_MEMORY_SCOPE_AGENT);
            out[0] = a1 + cr * 1e-5f;
            out[1 + BL] = a2;
        }
    }
}

extern "C" void kernel_launch(void* const* d_in, const int* in_sizes, int n_in,
                              void* d_out, int out_size, void* d_ws, size_t ws_size,
                              hipStream_t stream) {
    const int* q_data = (const int*)d_in[0];
    const int* qa_data = (const int*)d_in[1];
    const int* pid_data = (const int*)d_in[2];
    const float* matrix = (const float*)d_in[3];
    const float* target = (const float*)d_in[4];
    const float* q_emb = (const float*)d_in[5];
    const float* qa_emb = (const float*)d_in[6];
    const float* q_emb_diff = (const float*)d_in[7];
    const float* qa_emb_diff = (const float*)d_in[8];
    const float* diff_parm = (const float*)d_in[9];
    const float* w_ih = (const float*)d_in[10];
    const float* w_hh = (const float*)d_in[11];
    const float* b_ih = (const float*)d_in[12];
    const float* b_hh = (const float*)d_in[13];
    const float* fc_w = (const float*)d_in[14];
    const float* fc_b = (const float*)d_in[15];
    float* out = (float*)d_out;
    float* W = (float*)d_ws;

    float* acc = W + OFF_ACC;
    unsigned int* cells = (unsigned int*)(W + OFF_CELLS);
    float* hA = W + OFF_HA;
    float* Aq = W + OFF_AQ;
    float* Dq = W + OFF_DQ;
    float* Bqa = W + OFF_BQA;
    float* Cqa = W + OFF_CQA;
    float* cregs = W + OFF_CREGS;
    float* M2 = W + OFF_M2;
    float* mb = W + OFF_MB;
    int* qint = (int*)(W + OFF_QINT);
    int* qaint = (int*)(W + OFF_QAINT);
    float* pidf = W + OFF_PIDF;

    // single prep launch (M2 first = LPT; duals; mb; meta->creg slots; hA + acc/cells zero)
    prep_all<<<679, 256, 0, stream>>>(
        q_emb, q_emb_diff, qa_emb, qa_emb_diff, w_ih, b_ih,
        Aq, Dq, Bqa, Cqa, matrix, fc_w, fc_b, M2, mb,
        q_data, qa_data, pid_data, diff_parm, qint, qaint, pidf, cregs, hA, W);

    // GRU: R10 loop protocol + fused mval + parallel tail stats/dina/loss/final
    gru_persist<<<GBLK, 512, 0, stream>>>(Aq, Dq, Bqa, Cqa, qint, qaint, pidf,
                                          w_hh, b_hh, hA, M2, mb, cells,
                                          target, out, acc, cregs);
}

// Round 13
// 972.349 us; speedup vs baseline: 1.1688x; 1.0062x over previous
//
#include <hip/hip_runtime.h>
#include <hip/hip_bf16.h>
#include <math.h>

// Problem constants
#define BB 64
#define LL 200
#define NQ 1024
#define DD 256
#define HH 512
#define QQ 1024
#define G3 1536   // 3*H
#define BL 12800  // B*L
#define GBLK 256  // persistent GRU grid: 1 block/CU

// ---------------- workspace layout (in floats) ----------------
#define OFF_ACC   ((size_t)0)                    // [1]=mse [2]=maskcnt
#define OFF_CELLS ((size_t)16)                   // 256 cells, 16B apart + done ctr (1024 uints)
#define OFF_HA    ((size_t)1056)                 // hA[2][64][512] batch-major
#define OFF_AQ    (OFF_HA + 65536)               // 1025*1536
#define OFF_DQ    (OFF_AQ + 1574400)
#define OFF_BQA   (OFF_DQ + 1574400)             // 2*1536
#define OFF_CQA   (OFF_BQA + 3072)
#define OFF_CREGS (OFF_CQA + 3072)               // 50 creg partial slots
#define OFF_FCWT  (OFF_CREGS + 393216)           // (unused)
#define OFF_M2    (OFF_FCWT + 524288)            // 1024*512
#define OFF_MB    (OFF_M2 + 524288)              // 1024
#define OFF_QINT  (OFF_MB + 1024)                // 12800 ints [B][L]
#define OFF_QAINT (OFF_QINT + 12800)
#define OFF_PIDF  (OFF_QAINT + 12800)

typedef float f32x4 __attribute__((ext_vector_type(4)));

__device__ __forceinline__ float wave_sum64(float v) {
    #pragma unroll
    for (int o = 32; o > 0; o >>= 1) v += __shfl_down(v, o, 64);
    return v;
}

// LLC-coherent (bypass L1/L2) ops
__device__ __forceinline__ f32x4 llc_load4(const float* p) {
    f32x4 v;
    asm volatile("global_load_dwordx4 %0, %1, off sc0 sc1" : "=v"(v) : "v"(p));
    return v;
}
__device__ __forceinline__ void llc_wait2(f32x4& a, f32x4& b) {
    asm volatile("s_waitcnt vmcnt(0)" : "+v"(a), "+v"(b));
}
__device__ __forceinline__ void llc_store1(float* p, float v) {
    asm volatile("global_store_dword %0, %1, off sc0 sc1" :: "v"(p), "v"(v) : "memory");
}

// quad (4-lane) butterfly sum via DPP quad_perm (VALU pipe, not LDS)
__device__ __forceinline__ float quad_sum(float v) {
    float t1 = __int_as_float(__builtin_amdgcn_update_dpp(
        0, __float_as_int(v), 0xB1, 0xF, 0xF, true));   // quad_perm xor1
    v += t1;
    float t2 = __int_as_float(__builtin_amdgcn_update_dpp(
        0, __float_as_int(v), 0x4E, 0xF, 0xF, true));   // quad_perm xor2
    return v + t2;
}

// -------- 128x64 NT GEMM tile body (verified; optional B = sum of halves) ----
__device__ __forceinline__ void gemm_nt_body(
    const float* __restrict__ A, int lda, const float* __restrict__ B, int ldb,
    float* __restrict__ C, int ldc, int M, int N, int K,
    const float* __restrict__ bias, int bm, int bn, int tid, bool sumB,
    float (*As)[129], float (*Bs)[65])
{
    const int tx = tid & 15, ty = tid >> 4;
    const int mm = tid >> 4, kk = tid & 15;
    float acc[8][4] = {};
    float ar[8], br[4];
    #pragma unroll
    for (int i = 0; i < 8; ++i) {
        int m = bm + mm + 16 * i;
        ar[i] = (m < M) ? A[(size_t)m * lda + kk] : 0.f;
    }
    #pragma unroll
    for (int i = 0; i < 4; ++i) {
        int n = bn + mm + 16 * i;
        br[i] = (n < N) ? (sumB ? (B[(size_t)n * ldb + kk] + B[(size_t)n * ldb + DD + kk])
                                : B[(size_t)n * ldb + kk]) : 0.f;
    }
    for (int k0 = 0; k0 < K; k0 += 16) {
        #pragma unroll
        for (int i = 0; i < 8; ++i) As[kk][mm + 16 * i] = ar[i];
        #pragma unroll
        for (int i = 0; i < 4; ++i) Bs[kk][mm + 16 * i] = br[i];
        __syncthreads();
        int kn = k0 + 16;
        if (kn < K) {
            #pragma unroll
            for (int i = 0; i < 8; ++i) {
                int m = bm + mm + 16 * i;
                ar[i] = (m < M) ? A[(size_t)m * lda + kn + kk] : 0.f;
            }
            #pragma unroll
            for (int i = 0; i < 4; ++i) {
                int n = bn + mm + 16 * i;
                br[i] = (n < N) ? (sumB ? (B[(size_t)n * ldb + kn + kk]
                                           + B[(size_t)n * ldb + DD + kn + kk])
                                        : B[(size_t)n * ldb + kn + kk]) : 0.f;
            }
        }
        #pragma unroll
        for (int kq = 0; kq < 16; ++kq) {
            float a[8], b[4];
            #pragma unroll
            for (int i = 0; i < 8; ++i) a[i] = As[kq][ty * 8 + i];
            #pragma unroll
            for (int j = 0; j < 4; ++j) b[j] = Bs[kq][tx * 4 + j];
            #pragma unroll
            for (int i = 0; i < 8; ++i)
                #pragma unroll
                for (int j = 0; j < 4; ++j) acc[i][j] += a[i] * b[j];
        }
        __syncthreads();
    }
    #pragma unroll
    for (int i = 0; i < 8; ++i) {
        int m = bm + ty * 8 + i;
        if (m >= M) continue;
        #pragma unroll
        for (int j = 0; j < 4; ++j) {
            int n = bn + tx * 4 + j;
            if (n >= N) continue;
            C[(size_t)m * ldc + n] = acc[i][j] + (bias ? bias[n] : 0.f);
        }
    }
}

// -------- 128x128 NT GEMM tile body (higher intensity: 64 MAC / 16 LDS reads) ----
__device__ __forceinline__ void gemm_nt_128(
    const float* __restrict__ A, int lda, const float* __restrict__ B, int ldb,
    float* __restrict__ C, int ldc, int M, int N, int K,
    int bm, int bn, int tid, bool sumB,
    float (*As)[132], float (*Bs)[132])
{
    const int tx = tid & 15, ty = tid >> 4;
    const int mm = tid >> 4, kk = tid & 15;
    float acc[8][8] = {};
    float ar[8], br[8];
    #pragma unroll
    for (int i = 0; i < 8; ++i) {
        int m = bm + mm + 16 * i;
        ar[i] = (m < M) ? A[(size_t)m * lda + kk] : 0.f;
        int n = bn + mm + 16 * i;
        br[i] = (n < N) ? (sumB ? (B[(size_t)n * ldb + kk] + B[(size_t)n * ldb + DD + kk])
                                : B[(size_t)n * ldb + kk]) : 0.f;
    }
    for (int k0 = 0; k0 < K; k0 += 16) {
        #pragma unroll
        for (int i = 0; i < 8; ++i) { As[kk][mm + 16 * i] = ar[i]; Bs[kk][mm + 16 * i] = br[i]; }
        __syncthreads();
        int kn = k0 + 16;
        if (kn < K) {
            #pragma unroll
            for (int i = 0; i < 8; ++i) {
                int m = bm + mm + 16 * i;
                ar[i] = (m < M) ? A[(size_t)m * lda + kn + kk] : 0.f;
                int n = bn + mm + 16 * i;
                br[i] = (n < N) ? (sumB ? (B[(size_t)n * ldb + kn + kk]
                                           + B[(size_t)n * ldb + DD + kn + kk])
                                        : B[(size_t)n * ldb + kn + kk]) : 0.f;
            }
        }
        #pragma unroll
        for (int kq = 0; kq < 16; ++kq) {
            float a[8], b[8];
            #pragma unroll
            for (int i = 0; i < 8; ++i) a[i] = As[kq][ty * 8 + i];
            #pragma unroll
            for (int j = 0; j < 8; ++j) b[j] = Bs[kq][tx * 8 + j];
            #pragma unroll
            for (int i = 0; i < 8; ++i)
                #pragma unroll
                for (int j = 0; j < 8; ++j) acc[i][j] += a[i] * b[j];
        }
        __syncthreads();
    }
    #pragma unroll
    for (int i = 0; i < 8; ++i) {
        int m = bm + ty * 8 + i;
        if (m >= M) continue;
        #pragma unroll
        for (int j = 0; j < 8; ++j) {
            int n = bn + tx * 8 + j;
            if (n >= N) continue;
            C[(size_t)m * ldc + n] = acc[i][j];
        }
    }
}

// ======== single prep launch: M2 + duals(+wsum folded) + mb + meta + zeroing ========
// widx   0..127: M2 = matrix . fc_w (NN 64x64 tile, K=1024)
// widx 128..343: Aq/Dq dual, 128x128 tiles (z = w>=108; 9x12 tiles)
// widx 344..391: Bqa/Cqa dual (z = w>=24)
// widx 392..395: mb = matrix . fc_b
// widx 396..445: meta (q/qa/pid; creg partial -> dedicated slot)
// widx 446..461: zero hA[2][64][512]
// widx 462:      zero W[0..1055] (acc + cells + done ctr)
__global__ __launch_bounds__(256) void prep_all(
    const float* __restrict__ q_emb, const float* __restrict__ q_emb_diff,
    const float* __restrict__ qa_emb, const float* __restrict__ qa_emb_diff,
    const float* __restrict__ w_ih, const float* __restrict__ b_ih,
    float* __restrict__ Aq, float* __restrict__ Dq,
    float* __restrict__ Bqa, float* __restrict__ Cqa,
    const float* __restrict__ matrix, const float* __restrict__ fc_w,
    const float* __restrict__ fc_b, float* __restrict__ M2, float* __restrict__ mb,
    const int* __restrict__ q_data, const int* __restrict__ qa_data,
    const int* __restrict__ pid_data, const float* __restrict__ diff_parm,
    int* __restrict__ qint, int* __restrict__ qaint, float* __restrict__ pidf,
    float* __restrict__ cregs, float* __restrict__ hA, float* __restrict__ Wbase)
{
    __shared__ float As2[16][132];
    __shared__ float Bs2[16][132];
    __shared__ float sm[4];
    const int tid = threadIdx.x;
    const int widx = blockIdx.x;

    if (widx < 128) {
        // M2 64x64 NN tile, K=1024 (uses sub-views of the big LDS arrays)
        float (*As)[132] = As2;
        const int bm = (widx >> 3) * 64, bn = (widx & 7) * 64;
        const int kk = tid & 15, mm = tid >> 4;
        const int nb = tid & 63, kb2 = tid >> 6;
        const int tx = tid & 15, ty = tid >> 4;
        float acc[4][4] = {};
        for (int k0 = 0; k0 < QQ; k0 += 16) {
            if (k0) __syncthreads();
            #pragma unroll
            for (int i = 0; i < 4; ++i)
                As[kk][mm + 16 * i] = matrix[(size_t)(bm + mm + 16 * i) * QQ + k0 + kk];
            #pragma unroll
            for (int i = 0; i < 4; ++i)
                Bs2[kb2 + 4 * i][nb] = fc_w[(size_t)(k0 + kb2 + 4 * i) * HH + bn + nb];
            __syncthreads();
            #pragma unroll
            for (int kq = 0; kq < 16; ++kq) {
                float a[4], b[4];
                #pragma unroll
                for (int i = 0; i < 4; ++i) a[i] = As[kq][ty * 4 + i];
                #pragma unroll
                for (int j = 0; j < 4; ++j) b[j] = Bs2[kq][tx * 4 + j];
                #pragma unroll
                for (int i = 0; i < 4; ++i)
                    #pragma unroll
                    for (int j = 0; j < 4; ++j) acc[i][j] += a[i] * b[j];
            }
        }
        #pragma unroll
        for (int i = 0; i < 4; ++i)
            #pragma unroll
            for (int j = 0; j < 4; ++j)
                M2[(size_t)(bm + ty * 4 + i) * HH + bn + tx * 4 + j] = acc[i][j];
        return;
    }
    if (widx < 344) {
        const int w2 = widx - 128;
        const int z = w2 >= 108;
        const int w3 = z ? w2 - 108 : w2;
        const int bm = (w3 / 12) * 128, bn = (w3 % 12) * 128;
        // z=0: Aq = q_emb . (W1+W2)^T (wsum folded); z=1: Dq = q_emb_diff . W2^T
        gemm_nt_128(z ? q_emb_diff : q_emb, DD,
                    z ? (w_ih + DD) : w_ih, 2 * DD,
                    z ? Dq : Aq, G3, NQ + 1, G3, DD,
                    bm, bn, tid, !z, As2, Bs2);
        return;
    }
    if (widx < 392) {
        const int w2 = widx - 344;
        const int z = w2 >= 24;
        const int bn = (z ? w2 - 24 : w2) * 64;
        gemm_nt_body(z ? qa_emb_diff : qa_emb, DD,
                     w_ih, 2 * DD,
                     z ? Cqa : Bqa, G3, 2, G3, DD,
                     z ? nullptr : b_ih, 0, bn, tid, false,
                     (float (*)[129])As2, (float (*)[65])Bs2);
        return;
    }
    if (widx < 396) {
        // mb rows: 4 blocks x 4 waves x 64 rows
        const int wv2 = tid >> 6, lane2 = tid & 63;
        const int kb = (widx - 392) * 256 + wv2 * 64;
        for (int i = 0; i < 64; ++i) {
            const float* mrow = matrix + (size_t)(kb + i) * QQ;
            float sacc = 0.f;
            #pragma unroll
            for (int j = 0; j < 16; ++j)
                sacc += mrow[lane2 + 64 * j] * fc_b[lane2 + 64 * j];
            sacc = wave_sum64(sacc);
            if (lane2 == 0) mb[kb + i] = sacc;
        }
        return;
    }
    if (widx < 446) {
        // meta; creg partial goes to a per-block slot (no atomic, slot fully written)
        int r = (widx - 396) * 256 + tid;
        float pp = 0.f;
        if (r < BL) {
            int q = q_data[r];
            qint[r] = q;
            qaint[r] = (qa_data[r] - q) / NQ;
            float pid = diff_parm[pid_data[r]];
            pidf[r] = pid;
            pp = pid * pid;
        }
        pp = wave_sum64(pp);
        int lane = tid & 63, w = tid >> 6;
        if (lane == 0) sm[w] = pp;
        __syncthreads();
        if (tid == 0) cregs[widx - 396] = sm[0] + sm[1] + sm[2] + sm[3];
        return;
    }
    if (widx < 462) {
        // zero hA (2*64*512 = 16 blocks x 4096 floats)
        float* dst = hA + (size_t)(widx - 446) * 4096 + tid;
        #pragma unroll
        for (int i = 0; i < 16; ++i) dst[i * 256] = 0.f;
        return;
    }
    // widx == 462: zero acc + cells + done ctr (W[0..1055])
    for (int i = tid; i < 1056; i += 256) Wbase[i] = 0.f;
}

// ======= persistent GRU (R12-876 protocol) + fused mval + parallel tail ======
// 256 blocks = 8 bg x 32 ug; block = 8 batches x 16 units; weights in regs; per-wave
// LLC h staging; 3 barriers/step; tid<128 epilogue; wave-0-only poll; in-chain xg
// gather; meta in LDS; wave-2 M2 prefetch. Only change vs R12: poll backoff
// s_sleep(2)->s_sleep(1) (halves discovery quantum on the 200-step chain).
__global__ __launch_bounds__(512) void gru_persist(
    const float* __restrict__ Aq,      // [1025][1536]
    const float* __restrict__ Dq,      // [1025][1536]
    const float* __restrict__ Bqa,     // [2][1536]  (includes b_ih)
    const float* __restrict__ Cqa,     // [2][1536]
    const int* __restrict__ qint,      // [B][L]
    const int* __restrict__ qaint,     // [B][L]
    const float* __restrict__ pidf,    // [B][L]
    const float* __restrict__ w_hh,    // [1536][512]
    const float* __restrict__ b_hh,    // [1536]
    float* __restrict__ hA,            // [2][64][512]  (batch-major)
    const float* __restrict__ M2,      // [1024][512]
    const float* __restrict__ mbv,     // [1024]
    unsigned int* __restrict__ cells,  // 256 cells, 16B apart; [1021]=done ctr
    const float* __restrict__ target,  // [B][L]
    float* __restrict__ out,           // [1 + BL + 1]
    float* __restrict__ acc_g,         // [1]=mse [2]=cnt
    const float* __restrict__ cregs)   // [50] creg partials
{
    __shared__ float hs[8][512];          // per-wave staged h slice: [wave][b*64 + swz(col)]
    __shared__ float part[8][3][16][8];   // wave partials [wave][gate][unit][b(rotated)]
    __shared__ float bqs[2][3][16];       // Bqa slice for this block's 16 units
    __shared__ float cqs[2][3][16];       // Cqa slice
    __shared__ int smq[8][200];           // per-batch meta, whole sequence
    __shared__ int smqa[8][200];
    __shared__ float smp[8][200];
    __shared__ float mvbuf[LL];           // fused-mval ring (blocks ug<8)

    const int tid = threadIdx.x;
    const int bid = blockIdx.x;
    const int bg = bid >> 5;              // batch group 0..7 (8 batches)
    const int ug = bid & 31;
    const int j0 = ug * 16;               // first unit of this block
    const int wv = tid >> 6;              // 0..7 k-slice (64 k each)
    const int lane = tid & 63;
    const int g = lane >> 2;              // unit offset 0..15
    const int s = lane & 3;               // k sub-slice 0..3

    // ---- one-time LDS preloads: Bqa/Cqa slices + full meta sequence
    if (tid < 96) {
        const int qa = tid / 48, rem = tid - qa * 48;
        const int gate = rem >> 4, u = rem & 15;
        bqs[qa][gate][u] = Bqa[(size_t)qa * G3 + gate * HH + j0 + u];
        cqs[qa][gate][u] = Cqa[(size_t)qa * G3 + gate * HH + j0 + u];
    }
    for (int i = tid; i < 8 * LL; i += 512) {
        const int c = i / LL, tt = i - c * LL;
        const int col = bg * 8 + c;
        smq[c][tt] = qint[col * LL + tt];
        smqa[c][tt] = qaint[col * LL + tt];
        smp[c][tt] = pidf[col * LL + tt];
    }

    // ---- w_hh fragment in registers: 3 gates x 4 q x f32x4 = 48 floats/lane
    f32x4 ws4[3][4];
    #pragma unroll
    for (int gate = 0; gate < 3; ++gate)
        #pragma unroll
        for (int q = 0; q < 4; ++q)
            ws4[gate][q] = *(const f32x4*)&w_hh[
                (size_t)(gate * HH + j0 + g) * HH + wv * 64 + q * 16 + s * 4];

    // epilogue mapping (tid<128): unit eu, batch eb
    const int eu = tid >> 3;              // 0..15 when tid<128
    const int eb = tid & 7;
    float bhr = 0.f, bhz = 0.f, bhn = 0.f;
    if (tid < 128) {
        bhr = b_hh[j0 + eu];
        bhz = b_hh[HH + j0 + eu];
        bhn = b_hh[2 * HH + j0 + eu];
    }

    // staging split: lane's two 16B chunks of the wave's [8 b][64 k] slice
    const int b0 = lane >> 4;             // rows b0 and b0+4
    const int c0 = (lane & 15) * 4;       // col within k-slice

    __syncthreads();                      // bqs/cqs/meta visible

    for (int t = 0; t < LL; ++t) {
        // xg gather (waves 0-1; L3-resident tables; drained at the stage wait)
        float xr = 0.f, xz = 0.f, xn = 0.f;
        if (tid < 128) {
            const int q = smq[eb][t];
            const int qa = smqa[eb][t];
            const float pid = smp[eb][t];
            const float* aq = Aq + (size_t)q * G3 + j0 + eu;
            const float* dq = Dq + (size_t)q * G3 + j0 + eu;
            float ar_ = aq[0], az_ = aq[HH], an_ = aq[2 * HH];
            float dr_ = dq[0], dz_ = dq[HH], dn_ = dq[2 * HH];
            xr = ar_ + bqs[qa][0][eu] + pid * (cqs[qa][0][eu] + dr_);
            xz = az_ + bqs[qa][1][eu] + pid * (cqs[qa][1][eu] + dz_);
            xn = an_ + bqs[qa][2][eu] + pid * (cqs[qa][2][eu] + dn_);
        }
        // wave-2 (ug<8): prefetch M2 row + mb for mval[t-1] (drains under the poll)
        f32x4 m2a = {0.f, 0.f, 0.f, 0.f}, m2b = {0.f, 0.f, 0.f, 0.f};
        float mbq = 0.f;
        if (wv == 2 && ug < 8 && t >= 1) {
            const int q = smq[ug][t - 1] - 1;
            const float* m2r = M2 + (size_t)q * HH + lane * 8;
            m2a = *(const f32x4*)m2r;
            m2b = *(const f32x4*)(m2r + 4);
            mbq = mbv[q];
        }
        // wave 0 ONLY: poll the 32 producers (others wait at the cheap barrier)
        if (t && tid < 64) {
            const unsigned want = (unsigned)t;
            for (;;) {
                unsigned v = want;
                if (lane < 32)
                    v = __hip_atomic_load(&cells[(bg * 32 + lane) * 4],
                                          __ATOMIC_RELAXED, __HIP_MEMORY_SCOPE_AGENT);
                if (__all((int)(v >= want))) break;
                __builtin_amdgcn_s_sleep(1);
            }
        }
        __syncthreads();

        // ---- stage h[t&1] slice (coherent LLC loads, dense 1KB/wave/inst)
        {
            const float* hcur = hA + (size_t)(t & 1) * (HH * BB);
            const float* p0 = hcur + (size_t)(bg * 8 + b0) * HH + wv * 64 + c0;
            f32x4 va = llc_load4(p0);
            f32x4 vb = llc_load4(p0 + 4 * HH);
            llc_wait2(va, vb);
            *(f32x4*)&hs[wv][b0 * 64 + ((c0 + 8 * b0) & 63)] = va;
            *(f32x4*)&hs[wv][(b0 + 4) * 64 + ((c0 + 8 * b0 + 32) & 63)] = vb;
        }

        // ---- FMA: per-lane ds_read_b128 + 384 v_fma
        float acc[3][8];
        #pragma unroll
        for (int gate = 0; gate < 3; ++gate) {
            #pragma unroll
            for (int b = 0; b < 8; ++b) acc[gate][b] = 0.f;
        }
        #pragma unroll
        for (int q = 0; q < 4; ++q) {
            const int cb = q * 16 + s * 4;
            #pragma unroll
            for (int b = 0; b < 8; ++b) {
                f32x4 h4 = *(const f32x4*)&hs[wv][b * 64 + ((cb + 8 * b) & 63)];
                #pragma unroll
                for (int gate = 0; gate < 3; ++gate) {
                    acc[gate][b] += ws4[gate][q].x * h4.x + ws4[gate][q].y * h4.y
                                  + ws4[gate][q].z * h4.z + ws4[gate][q].w * h4.w;
                }
            }
        }

        // k-reduce across the 4 s-lanes of each quad (VALU DPP)
        #pragma unroll
        for (int gate = 0; gate < 3; ++gate)
            #pragma unroll
            for (int b = 0; b < 8; ++b)
                acc[gate][b] = quad_sum(acc[gate][b]);

        // s-lane s (<3) writes gate s partials, columns rotated to spread banks.
        if (s < 3) {
            const int rot = (2 * ((g >> 2) + s)) & 7;
            #pragma unroll
            for (int hp = 0; hp < 4; ++hp) {
                const int b = hp * 2;
                float e0 = (s == 0) ? acc[0][b]     : (s == 1) ? acc[1][b]     : acc[2][b];
                float e1 = (s == 0) ? acc[0][b + 1] : (s == 1) ? acc[1][b + 1] : acc[2][b + 1];
                const int bp = (b + rot) & 7;
                *(float2*)&part[wv][s][g][bp] = make_float2(e0, e1);
            }
        }
        __syncthreads();   // sync1: partials + hs stable

        // ---- fused mval (wave 2, ug<8): prefetched M2 regs + hs -> LDS ring
        if (wv == 2 && ug < 8 && t >= 1) {
            float sacc = 0.f;
            #pragma unroll
            for (int j = 0; j < 8; ++j) {
                const int k = lane * 8 + j;
                const float hv = hs[k >> 6][ug * 64 + (((k & 63) + 8 * ug) & 63)];
                const float mvw = (j == 0) ? m2a.x : (j == 1) ? m2a.y : (j == 2) ? m2a.z
                                : (j == 3) ? m2a.w : (j == 4) ? m2b.x : (j == 5) ? m2b.y
                                : (j == 6) ? m2b.z : m2b.w;
                sacc += hv * mvw;
            }
            sacc = wave_sum64(sacc);
            if (lane == 0) {
                float sv = sacc + mbq;
                mvbuf[t - 1] = (sv >= 0.4f) ? 1.0f : sv;
            }
        }

        // ---- 8-wave reduce + gates + h store (tid<128: 16 units x 8 batches)
        if (tid < 128) {
            const int rb = eu >> 2;
            const int bp0 = (eb + 2 * (rb + 0)) & 7;
            const int bp1 = (eb + 2 * (rb + 1)) & 7;
            const int bp2 = (eb + 2 * (rb + 2)) & 7;
            float sg0 = 0.f, sg1 = 0.f, sg2 = 0.f;
            #pragma unroll
            for (int w = 0; w < 8; ++w) {
                sg0 += part[w][0][eu][bp0];
                sg1 += part[w][1][eu][bp1];
                sg2 += part[w][2][eu][bp2];
            }
            const int ku = j0 + eu;
            float hprev = hs[ku >> 6][eb * 64 + (((ku & 63) + 8 * eb) & 63)];
            float rg = 1.f / (1.f + expf(-(xr + sg0 + bhr)));
            float zg = 1.f / (1.f + expf(-(xz + sg1 + bhz)));
            float ng = tanhf(xn + rg * (sg2 + bhn));
            float hn = (1.f - zg) * ng + zg * hprev;
            llc_store1(hA + (size_t)((t + 1) & 1) * (HH * BB)
                          + (size_t)(bg * 8 + eb) * HH + ku, hn);
            asm volatile("s_waitcnt vmcnt(0)" ::: "memory");
        }
        __syncthreads();   // sync2: epilogue h-stores drained; hs/part reusable
        if (tid == 0)
            __hip_atomic_store(&cells[bid * 4], (unsigned)(t + 1),
                               __ATOMIC_RELAXED, __HIP_MEMORY_SCOPE_AGENT);
    }

    // ================= tail: blocks ug<8 (one per batch) only =================
    if (ug >= 8) return;
    // poll gen LL, stage h_{LL-1}, compute mval[LL-1]
    if (tid < 64) {
        const unsigned want = (unsigned)LL;
        for (;;) {
            unsigned v = want;
            if (lane < 32)
                v = __hip_atomic_load(&cells[(bg * 32 + lane) * 4],
                                      __ATOMIC_RELAXED, __HIP_MEMORY_SCOPE_AGENT);
            if (__all((int)(v >= want))) break;
            __builtin_amdgcn_s_sleep(1);
        }
    }
    __syncthreads();
    {
        const float* hcur = hA + (size_t)(LL & 1) * (HH * BB);
        const float* p0 = hcur + (size_t)(bg * 8 + b0) * HH + wv * 64 + c0;
        f32x4 va = llc_load4(p0);
        f32x4 vb = llc_load4(p0 + 4 * HH);
        llc_wait2(va, vb);
        *(f32x4*)&hs[wv][b0 * 64 + ((c0 + 8 * b0) & 63)] = va;
        *(f32x4*)&hs[wv][(b0 + 4) * 64 + ((c0 + 8 * b0 + 32) & 63)] = vb;
    }
    __syncthreads();
    if (wv == 2) {
        const int q = smq[ug][LL - 1] - 1;
        const float* m2r = M2 + (size_t)q * HH + lane * 8;
        f32x4 ma = *(const f32x4*)m2r;
        f32x4 mc4 = *(const f32x4*)(m2r + 4);
        float sacc = 0.f;
        #pragma unroll
        for (int j = 0; j < 8; ++j) {
            const int k = lane * 8 + j;
            const float hv = hs[k >> 6][ug * 64 + (((k & 63) + 8 * ug) & 63)];
            const float mvw = (j == 0) ? ma.x : (j == 1) ? ma.y : (j == 2) ? ma.z
                            : (j == 3) ? ma.w : (j == 4) ? mc4.x : (j == 5) ? mc4.y
                            : (j == 6) ? mc4.z : mc4.w;
            sacc += hv * mvw;
        }
        sacc = wave_sum64(sacc);
        if (lane == 0) {
            float sv = sacc + mbv[q];
            mvbuf[LL - 1] = (sv >= 0.4f) ? 1.0f : sv;
        }
    }
    __syncthreads();

    // ---- fused stats + PARALLEL DINA + loss for batch bq (all LDS-resident)
    const int bq = bg * 8 + ug;
    float* preds_l = &hs[4][0];        // 200 floats (aliases dead hs)
    float* s_mc = &part[0][0][0][0];   // stats (alias dead part)
    float* s_mi = s_mc + 256;
    float* s_nmc = s_mc + 512;
    float* s_aa = s_mc + 768;
    float* sred = &bqs[0][0][0];       // 8 floats (aliases dead bqs)
    float* cred = sred + 8;
    if (tid < LL) {
        const int qt = smq[ug][tid];
        float smc = 0.f, smi = 0.f, snmc = 0.f, saa = 0.f;
        for (int k = 0; k <= tid; ++k) {
            if (smq[ug][k] == qt) {
                saa += 1.f;
                if (k < tid) {
                    float mk = (mvbuf[k] == 1.f) ? 1.f : 0.f;
                    float nk = (mvbuf[k] == 0.f) ? 1.f : 0.f;
                    float a1 = (smqa[ug][k] == 1) ? 1.f : 0.f;
                    smc += a1 * mk;
                    smi += (1.f - a1) * mk;
                    snmc += (1.f - a1) * nk;
                }
            }
        }
        s_mc[tid] = smc;
        s_mi[tid] = smi;
        s_nmc[tid] = snmc;
        s_aa[tid] = saa;
    }
    __syncthreads();
    // DINA, parallel per t: ng/ns depend only on the most recent prior same-q
    // step with the matching us flag (guess written only when !us; slip only when us).
    if (tid < LL) {
        const int t = tid;
        const int qt = smq[ug][t];
        const float m = mvbuf[t];
        const int qa = smqa[ug][t];
        const bool ust = (m == 1.f) && (qa == 0);
        float gval = 0.f, sval = 0.f;   // init guess/slip = 0
        bool gf = false, sf = false;
        for (int k = t - 1; k >= 0; --k) {
            if (gf && sf) break;
            if (smq[ug][k] != qt) continue;
            const float mk = mvbuf[k];
            const int qak = smqa[ug][k];
            const bool usk = (mk == 1.f) && (qak == 0);
            if (usk) {
                if (!sf) { sval = s_mi[k] / s_aa[k]; sf = true; }
            } else {
                if (!gf) {
                    gval = (mk == 1.f) ? s_mc[k] / s_aa[k]
                         : ((qak == 0) ? 1.f - s_nmc[k] / s_aa[k] : s_nmc[k] / s_aa[k]);
                    gf = true;
                }
            }
        }
        const float g_upd = (m == 1.f) ? s_mc[t] / s_aa[t]
                          : ((qa == 0) ? 1.f - s_nmc[t] / s_aa[t] : s_nmc[t] / s_aa[t]);
        const float ng = ust ? gval : g_upd;
        const float ns = ust ? s_mi[t] / s_aa[t] : sval;
        preds_l[t] = (1.f - ns) * (m * ng + (1.f - ns) * (1.f - m));
    }
    __syncthreads();
    if (tid < 256) {
        float lm = 0.f, lc = 0.f;
        if (tid < LL) {
            const float p = preds_l[tid];
            const float lab = target[bq * LL + tid];
            const float msk = (lab > -0.9f) ? 1.f : 0.f;
            const float d = p - lab;
            lm = d * d * msk;
            lc = msk;
            out[1 + bq * LL + tid] = 1.f / (1.f + expf(-p));
        }
        lm = wave_sum64(lm);
        lc = wave_sum64(lc);
        if (lane == 0) { sred[wv] = lm; cred[wv] = lc; }
    }
    __syncthreads();
    if (tid == 0) {
        atomicAdd(&acc_g[1], sred[0] + sred[1] + sred[2] + sred[3]);
        atomicAdd(&acc_g[2], cred[0] + cred[1] + cred[2] + cred[3]);
        const unsigned old = __hip_atomic_fetch_add(&cells[1021], 1u,
                                                    __ATOMIC_ACQ_REL,
                                                    __HIP_MEMORY_SCOPE_AGENT);
        if (old == 63) {
            float cr = 0.f;
            for (int i = 0; i < 50; ++i) cr += cregs[i];
            float a1 = __hip_atomic_load(&acc_g[1], __ATOMIC_RELAXED, __HIP_MEMORY_SCOPE_AGENT);
            float a2 = __hip_atomic_load(&acc_g[2], __ATOMIC_RELAXED, __HIP_MEMORY_SCOPE_AGENT);
            out[0] = a1 + cr * 1e-5f;
            out[1 + BL] = a2;
        }
    }
}

extern "C" void kernel_launch(void* const* d_in, const int* in_sizes, int n_in,
                              void* d_out, int out_size, void* d_ws, size_t ws_size,
                              hipStream_t stream) {
    const int* q_data = (const int*)d_in[0];
    const int* qa_data = (const int*)d_in[1];
    const int* pid_data = (const int*)d_in[2];
    const float* matrix = (const float*)d_in[3];
    const float* target = (const float*)d_in[4];
    const float* q_emb = (const float*)d_in[5];
    const float* qa_emb = (const float*)d_in[6];
    const float* q_emb_diff = (const float*)d_in[7];
    const float* qa_emb_diff = (const float*)d_in[8];
    const float* diff_parm = (const float*)d_in[9];
    const float* w_ih = (const float*)d_in[10];
    const float* w_hh = (const float*)d_in[11];
    const float* b_ih = (const float*)d_in[12];
    const float* b_hh = (const float*)d_in[13];
    const float* fc_w = (const float*)d_in[14];
    const float* fc_b = (const float*)d_in[15];
    float* out = (float*)d_out;
    float* W = (float*)d_ws;

    float* acc = W + OFF_ACC;
    unsigned int* cells = (unsigned int*)(W + OFF_CELLS);
    float* hA = W + OFF_HA;
    float* Aq = W + OFF_AQ;
    float* Dq = W + OFF_DQ;
    float* Bqa = W + OFF_BQA;
    float* Cqa = W + OFF_CQA;
    float* cregs = W + OFF_CREGS;
    float* M2 = W + OFF_M2;
    float* mb = W + OFF_MB;
    int* qint = (int*)(W + OFF_QINT);
    int* qaint = (int*)(W + OFF_QAINT);
    float* pidf = W + OFF_PIDF;

    // single prep launch (M2 first = LPT; 128x128 duals; mb; meta; hA + acc/cells zero)
    prep_all<<<463, 256, 0, stream>>>(
        q_emb, q_emb_diff, qa_emb, qa_emb_diff, w_ih, b_ih,
        Aq, Dq, Bqa, Cqa, matrix, fc_w, fc_b, M2, mb,
        q_data, qa_data, pid_data, diff_parm, qint, qaint, pidf, cregs, hA, W);

    // GRU: R12 protocol (sleep(1) poll) + fused mval + parallel tail
    gru_persist<<<GBLK, 512, 0, stream>>>(Aq, Dq, Bqa, Cqa, qint, qaint, pidf,
                                          w_hh, b_hh, hA, M2, mb, cells,
                                          target, out, acc, cregs);
}